// Round 5
// baseline (400.456 us; speedup 1.0000x reference)
//
#include <hip/hip_runtime.h>
#include <hip/hip_bf16.h>

typedef __bf16 bf16;
typedef __attribute__((ext_vector_type(8))) __bf16 bf16x8;
typedef __attribute__((ext_vector_type(4))) float f32x4;

#define MFMA16(a, b, c) __builtin_amdgcn_mfma_f32_16x16x32_bf16((a), (b), (c), 0, 0, 0)

// B=2, S=2048, D=512, H=8, hd=64, G=4. All I/O float32; bf16 MFMA compute.
static constexpr float EPS = 1e-5f;
static constexpr float LAMBDA_INIT = 0.2f;

// Load 8 consecutive f32 (32B, 16B-aligned) and convert to bf16x8.
__device__ __forceinline__ bf16x8 cvt8(const float* p) {
    const f32x4 a = *(const f32x4*)p;
    const f32x4 b = *(const f32x4*)(p + 4);
    bf16x8 r;
    r[0] = (bf16)a[0]; r[1] = (bf16)a[1]; r[2] = (bf16)a[2]; r[3] = (bf16)a[3];
    r[4] = (bf16)b[0]; r[5] = (bf16)b[1]; r[6] = (bf16)b[2]; r[7] = (bf16)b[3];
    return r;
}

// ---------------------------------------------------------------------------
// Kernel 1: fused QKV projection GEMM (f32 in -> bf16 out).  [unchanged]
// ---------------------------------------------------------------------------
__global__ __launch_bounds__(256) void proj_kernel(
    const float* __restrict__ x,
    const float* __restrict__ q1w, const float* __restrict__ k1w,
    const float* __restrict__ q2w, const float* __restrict__ k2w,
    const float* __restrict__ vw,
    const float* __restrict__ k1b, const float* __restrict__ k2b,
    bf16* __restrict__ q1o, bf16* __restrict__ k1o,
    bf16* __restrict__ q2o, bf16* __restrict__ k2o,
    bf16* __restrict__ vto)
{
    const int lane = threadIdx.x & 63;
    const int wave = threadIdx.x >> 6;
    const int l15 = lane & 15, quad = lane >> 4;

    const int tile = blockIdx.x * 4 + wave;      // 64 m-tiles x 40 n-tiles
    const int mt = tile / 40;
    const int nt = tile % 40;
    const int wsel = nt >> 3;
    const int nb = (nt & 7) * 64;

    const float* W = (wsel == 0) ? q1w : (wsel == 1) ? k1w :
                     (wsel == 2) ? q2w : (wsel == 3) ? k2w : vw;

    const float* ap[4];
    const float* bp[4];
#pragma unroll
    for (int i = 0; i < 4; ++i)
        ap[i] = x + (size_t)(mt * 64 + i * 16 + l15) * 512 + quad * 8;
#pragma unroll
    for (int j = 0; j < 4; ++j)
        bp[j] = W + (size_t)(nb + j * 16 + l15) * 512 + quad * 8;

    f32x4 acc[4][4];
#pragma unroll
    for (int i = 0; i < 4; ++i)
#pragma unroll
        for (int j = 0; j < 4; ++j)
            acc[i][j] = (f32x4){0.f, 0.f, 0.f, 0.f};

    for (int kk = 0; kk < 16; ++kk) {
        bf16x8 af[4], bfr[4];
#pragma unroll
        for (int i = 0; i < 4; ++i) af[i] = cvt8(ap[i] + kk * 32);
#pragma unroll
        for (int j = 0; j < 4; ++j) bfr[j] = cvt8(bp[j] + kk * 32);
#pragma unroll
        for (int i = 0; i < 4; ++i)
#pragma unroll
            for (int j = 0; j < 4; ++j)
                acc[i][j] = MFMA16(af[i], bfr[j], acc[i][j]);
    }

    const float scale = (wsel == 0 || wsel == 2) ? 0.125f : 1.0f;
#pragma unroll
    for (int j = 0; j < 4; ++j) {
        const int ncol = nb + j * 16 + l15;
        float bias = 0.f;
        if (wsel == 1) bias = k1b[ncol];
        if (wsel == 3) bias = k2b[ncol];
        const int h = ncol >> 6, hd = ncol & 63;
#pragma unroll
        for (int i = 0; i < 4; ++i) {
#pragma unroll
            for (int r = 0; r < 4; ++r) {
                const int m = mt * 64 + i * 16 + quad * 4 + r;
                const int bidx = m >> 11, s = m & 2047;
                const float v = acc[i][j][r] * scale + bias;
                if (wsel == 4) {
                    vto[((size_t)(bidx * 8 + h) * 64 + hd) * 2048 + s] = (bf16)v;
                } else {
                    bf16* dst = (wsel == 0) ? q1o : (wsel == 1) ? k1o :
                                (wsel == 2) ? q2o : k2o;
                    dst[((size_t)(bidx * 8 + h) * 2048 + s) * 64 + hd] = (bf16)v;
                }
            }
        }
    }
}

// ---------------------------------------------------------------------------
// Kernel 2: dual-stream flash attention, K-split across waves.
// Block = 4 waves, ONE 16-query tile; wave w covers keys [w*512, w*512+512).
// No-max softmax (scores bounded) => partial (O,l) sum directly across waves.
// Barrier-free main loop (wave-private LDS P-transpose, single drain/iter);
// 3-barrier pairwise cross-wave reduction in the epilogue.
// Grid = B*H*128 = 2048 blocks.
// ---------------------------------------------------------------------------
__global__ __launch_bounds__(256) void attn_kernel(
    const bf16* __restrict__ q1, const bf16* __restrict__ k1,
    const bf16* __restrict__ q2, const bf16* __restrict__ k2,
    const bf16* __restrict__ vt,
    const float* __restrict__ lq1, const float* __restrict__ lk1,
    const float* __restrict__ lq2, const float* __restrict__ lk2,
    bf16* __restrict__ o)
{
    __shared__ __align__(16) bf16 pshm[8][16 * 32];    // 2 transpose bufs/wave (8 KB)
    __shared__ __align__(16) f32x4 rbuf[2][8][64];     // pairwise O-reduce (16 KB)
    __shared__ float lbuf[4][2][16];                   // per-wave row l sums (512 B)

    const int lane = threadIdx.x & 63;
    const int wave = threadIdx.x >> 6;
    const int l15 = lane & 15, quad = lane >> 4;

    const int bh = blockIdx.x >> 7;      // 0..15
    const int qt = blockIdx.x & 127;     // 16-query tile
    const int b = bh >> 3, h = bh & 7;
    const int qbase = qt * 16;

    const bf16* q1p = q1 + ((size_t)bh * 2048 + qbase + l15) * 64 + quad * 8;
    const bf16* q2p = q2 + ((size_t)bh * 2048 + qbase + l15) * 64 + quad * 8;
    const bf16x8 q1f0 = *(const bf16x8*)(q1p);
    const bf16x8 q1f1 = *(const bf16x8*)(q1p + 32);
    const bf16x8 q2f0 = *(const bf16x8*)(q2p);
    const bf16x8 q2f1 = *(const bf16x8*)(q2p + 32);

    const bf16* k1base = k1 + (size_t)bh * 2048 * 64;
    const bf16* k2base = k2 + (size_t)bh * 2048 * 64;
    const bf16* vbase  = vt + (size_t)bh * 64 * 2048;

    f32x4 O1[4], O2[4];
    float l1[4], l2[4];
#pragma unroll
    for (int t = 0; t < 4; ++t) {
        O1[t] = (f32x4){0.f, 0.f, 0.f, 0.f};
        O2[t] = (f32x4){0.f, 0.f, 0.f, 0.f};
    }
#pragma unroll
    for (int r = 0; r < 4; ++r) { l1[r] = 0.f; l2[r] = 0.f; }

    bf16* pbuf1 = &pshm[wave * 2][0];
    bf16* pbuf2 = &pshm[wave * 2 + 1][0];

    const int kb0 = wave * 16;           // this wave's 16 key-blocks of 32
    for (int it = 0; it < 16; ++it) {
        const int kbase = (kb0 + it) * 32;

        const bf16* k1p = k1base + (size_t)(kbase + l15) * 64 + quad * 8;
        const bf16x8 k1t0a = *(const bf16x8*)(k1p);
        const bf16x8 k1t0b = *(const bf16x8*)(k1p + 32);
        const bf16x8 k1t1a = *(const bf16x8*)(k1p + 16 * 64);
        const bf16x8 k1t1b = *(const bf16x8*)(k1p + 16 * 64 + 32);

        const bf16* k2p = k2base + (size_t)(kbase + l15) * 64 + quad * 8;
        const bf16x8 k2t0a = *(const bf16x8*)(k2p);
        const bf16x8 k2t0b = *(const bf16x8*)(k2p + 32);
        const bf16x8 k2t1a = *(const bf16x8*)(k2p + 16 * 64);
        const bf16x8 k2t1b = *(const bf16x8*)(k2p + 16 * 64 + 32);

        const bf16* vp = vbase + (size_t)l15 * 2048 + kbase + quad * 8;
        const bf16x8 v0 = *(const bf16x8*)(vp);
        const bf16x8 v1 = *(const bf16x8*)(vp + 16 * 2048);
        const bf16x8 v2 = *(const bf16x8*)(vp + 32 * 2048);
        const bf16x8 v3 = *(const bf16x8*)(vp + 48 * 2048);

        f32x4 s1a = (f32x4){0.f, 0.f, 0.f, 0.f};
        s1a = MFMA16(q1f0, k1t0a, s1a);
        s1a = MFMA16(q1f1, k1t0b, s1a);
        f32x4 s1b = (f32x4){0.f, 0.f, 0.f, 0.f};
        s1b = MFMA16(q1f0, k1t1a, s1b);
        s1b = MFMA16(q1f1, k1t1b, s1b);

        f32x4 s2a = (f32x4){0.f, 0.f, 0.f, 0.f};
        s2a = MFMA16(q2f0, k2t0a, s2a);
        s2a = MFMA16(q2f1, k2t0b, s2a);
        f32x4 s2b = (f32x4){0.f, 0.f, 0.f, 0.f};
        s2b = MFMA16(q2f0, k2t1a, s2b);
        s2b = MFMA16(q2f1, k2t1b, s2b);

        float p1a[4], p1b[4], p2a[4], p2b[4];
#pragma unroll
        for (int r = 0; r < 4; ++r) {
            p1a[r] = __expf(s1a[r]);
            p1b[r] = __expf(s1b[r]);
            p2a[r] = __expf(s2a[r]);
            p2b[r] = __expf(s2b[r]);
            l1[r] += p1a[r] + p1b[r];
            l2[r] += p2a[r] + p2b[r];
        }

        // Both streams' P (16x32) C-layout -> wave-private LDS, one drain.
#pragma unroll
        for (int r = 0; r < 4; ++r) {
            pbuf1[(quad * 4 + r) * 32 + l15]      = (bf16)p1a[r];
            pbuf1[(quad * 4 + r) * 32 + 16 + l15] = (bf16)p1b[r];
            pbuf2[(quad * 4 + r) * 32 + l15]      = (bf16)p2a[r];
            pbuf2[(quad * 4 + r) * 32 + 16 + l15] = (bf16)p2b[r];
        }
        asm volatile("s_waitcnt lgkmcnt(0)" ::: "memory");
        const bf16x8 pfrag1 = *(const bf16x8*)(pbuf1 + l15 * 32 + quad * 8);
        const bf16x8 pfrag2 = *(const bf16x8*)(pbuf2 + l15 * 32 + quad * 8);

        O1[0] = MFMA16(pfrag1, v0, O1[0]);
        O1[1] = MFMA16(pfrag1, v1, O1[1]);
        O1[2] = MFMA16(pfrag1, v2, O1[2]);
        O1[3] = MFMA16(pfrag1, v3, O1[3]);
        O2[0] = MFMA16(pfrag2, v0, O2[0]);
        O2[1] = MFMA16(pfrag2, v1, O2[1]);
        O2[2] = MFMA16(pfrag2, v2, O2[2]);
        O2[3] = MFMA16(pfrag2, v3, O2[3]);
    }

    // Per-wave l: reduce over the 16 lanes holding each row's columns.
#pragma unroll
    for (int off = 1; off < 16; off <<= 1) {
#pragma unroll
        for (int r = 0; r < 4; ++r) {
            l1[r] += __shfl_xor(l1[r], off, 64);
            l2[r] += __shfl_xor(l2[r], off, 64);
        }
    }
    if (l15 == 0) {
#pragma unroll
        for (int r = 0; r < 4; ++r) {
            lbuf[wave][0][quad * 4 + r] = l1[r];
            lbuf[wave][1][quad * 4 + r] = l2[r];
        }
    }

    // Pairwise cross-wave O reduction: (0+=1, 2+=3), then (0+=2).
    if (wave == 1 || wave == 3) {
        const int widx = wave >> 1;
#pragma unroll
        for (int t = 0; t < 4; ++t) {
            rbuf[widx][t][lane]     = O1[t];
            rbuf[widx][t + 4][lane] = O2[t];
        }
    }
    __syncthreads();
    if (wave == 0 || wave == 2) {
        const int widx = wave >> 1;
#pragma unroll
        for (int t = 0; t < 4; ++t) {
            O1[t] += rbuf[widx][t][lane];
            O2[t] += rbuf[widx][t + 4][lane];
        }
    }
    __syncthreads();
    if (wave == 2) {
#pragma unroll
        for (int t = 0; t < 4; ++t) {
            rbuf[0][t][lane]     = O1[t];
            rbuf[0][t + 4][lane] = O2[t];
        }
    }
    __syncthreads();
    if (wave == 0) {
#pragma unroll
        for (int t = 0; t < 4; ++t) {
            O1[t] += rbuf[0][t][lane];
            O2[t] += rbuf[0][t + 4][lane];
        }
        float L1[4], L2[4];
#pragma unroll
        for (int r = 0; r < 4; ++r) {
            const int row = quad * 4 + r;
            L1[r] = lbuf[0][0][row] + lbuf[1][0][row] + lbuf[2][0][row] + lbuf[3][0][row];
            L2[r] = lbuf[0][1][row] + lbuf[1][1][row] + lbuf[2][1][row] + lbuf[3][1][row];
        }
        const float lam = __expf(lq1[h] * lk1[h]) - __expf(lq2[h] * lk2[h]) + LAMBDA_INIT;
#pragma unroll
        for (int r = 0; r < 4; ++r) {
            const float inv1 = 1.f / L1[r];
            const float inv2 = lam / L2[r];
            const int srow = qbase + quad * 4 + r;
#pragma unroll
            for (int t = 0; t < 4; ++t) {
                const float val = O1[t][r] * inv1 - O2[t][r] * inv2;
                o[((size_t)(b * 2048 + srow) * 512) + h * 64 + t * 16 + l15] = (bf16)val;
            }
        }
    }
}

// ---------------------------------------------------------------------------
// Kernel 3: GroupNorm stats over (128 channels x 2048 s) per (b,g). [unchanged]
// ---------------------------------------------------------------------------
__global__ __launch_bounds__(256) void gn_stats_kernel(
    const bf16* __restrict__ o, float* __restrict__ stats)
{
    const int bg = blockIdx.x >> 4;
    const int chunk = blockIdx.x & 15;
    const int b = bg >> 2, g = bg & 3;

    float sum = 0.f, sumsq = 0.f;
    for (int i = threadIdx.x; i < 128 * 128; i += 256) {
        const int sr = i >> 7, c = i & 127;
        const float v = (float)o[((size_t)(b * 2048 + chunk * 128 + sr) * 512) + g * 128 + c];
        sum += v; sumsq += v * v;
    }
#pragma unroll
    for (int off = 1; off < 64; off <<= 1) {
        sum += __shfl_xor(sum, off, 64);
        sumsq += __shfl_xor(sumsq, off, 64);
    }
    __shared__ float red[2][4];
    const int wave = threadIdx.x >> 6, lane = threadIdx.x & 63;
    if (lane == 0) { red[0][wave] = sum; red[1][wave] = sumsq; }
    __syncthreads();
    if (threadIdx.x == 0) {
        float s0 = 0.f, s1 = 0.f;
        for (int w = 0; w < 4; ++w) { s0 += red[0][w]; s1 += red[1][w]; }
        atomicAdd(&stats[bg * 2], s0);
        atomicAdd(&stats[bg * 2 + 1], s1);
    }
}

// ---------------------------------------------------------------------------
// Kernel 4: apply GroupNorm affine -> xn (bf16). [unchanged]
// ---------------------------------------------------------------------------
__global__ __launch_bounds__(256) void gn_apply_kernel(
    const bf16* __restrict__ o, const float* __restrict__ stats,
    const float* __restrict__ gnw, const float* __restrict__ gnb,
    bf16* __restrict__ xn)
{
    const int idx = blockIdx.x * 256 + threadIdx.x;
    const int base = idx * 8;
    const int c = base & 511;
    const int b = base >> 20;
    const int g = c >> 7;
    const int bg = b * 4 + g;

    const float N = 128.f * 2048.f;
    const float mu = stats[bg * 2] / N;
    const float var = stats[bg * 2 + 1] / N - mu * mu;
    const float rstd = rsqrtf(var + EPS);

    const bf16x8 vals = *(const bf16x8*)(o + base);
    bf16x8 out;
#pragma unroll
    for (int j = 0; j < 8; ++j) {
        const float w = gnw[c + j];
        const float bb = gnb[c + j];
        out[j] = (bf16)(((float)vals[j] - mu) * rstd * w + bb);
    }
    *(bf16x8*)(xn + base) = out;
}

// ---------------------------------------------------------------------------
// Kernel 5: output GEMM y = xn @ out_w^T + out_b, y f32. [unchanged]
// ---------------------------------------------------------------------------
__global__ __launch_bounds__(256) void out_gemm_kernel(
    const bf16* __restrict__ xn, const float* __restrict__ ow,
    const float* __restrict__ ob, float* __restrict__ y)
{
    const int lane = threadIdx.x & 63;
    const int wave = threadIdx.x >> 6;
    const int l15 = lane & 15, quad = lane >> 4;

    const int tile = blockIdx.x * 4 + wave;
    const int mt = tile >> 4;
    const int nt = tile & 15;

    const bf16* ap[4];
#pragma unroll
    for (int i = 0; i < 4; ++i)
        ap[i] = xn + (size_t)(mt * 64 + i * 16 + l15) * 512 + quad * 8;
    const float* bp[2];
#pragma unroll
    for (int j = 0; j < 2; ++j)
        bp[j] = ow + (size_t)(nt * 32 + j * 16 + l15) * 512 + quad * 8;

    f32x4 acc[4][2];
#pragma unroll
    for (int i = 0; i < 4; ++i)
#pragma unroll
        for (int j = 0; j < 2; ++j)
            acc[i][j] = (f32x4){0.f, 0.f, 0.f, 0.f};

    for (int kk = 0; kk < 16; ++kk) {
        bf16x8 af[4], bfr[2];
#pragma unroll
        for (int i = 0; i < 4; ++i) af[i] = *(const bf16x8*)(ap[i] + kk * 32);
#pragma unroll
        for (int j = 0; j < 2; ++j) bfr[j] = cvt8(bp[j] + kk * 32);
#pragma unroll
        for (int i = 0; i < 4; ++i)
#pragma unroll
            for (int j = 0; j < 2; ++j)
                acc[i][j] = MFMA16(af[i], bfr[j], acc[i][j]);
    }

#pragma unroll
    for (int j = 0; j < 2; ++j) {
        const int ncol = nt * 32 + j * 16 + l15;
        const float bias = ob[ncol];
#pragma unroll
        for (int i = 0; i < 4; ++i) {
#pragma unroll
            for (int r = 0; r < 4; ++r) {
                const int m = mt * 64 + i * 16 + quad * 4 + r;
                y[(size_t)m * 512 + ncol] = acc[i][j][r] + bias;
            }
        }
    }
}

// ---------------------------------------------------------------------------
extern "C" void kernel_launch(void* const* d_in, const int* in_sizes, int n_in,
                              void* d_out, int out_size, void* d_ws, size_t ws_size,
                              hipStream_t stream)
{
    const float* x   = (const float*)d_in[0];
    const float* K1w = (const float*)d_in[1];
    const float* K1b = (const float*)d_in[2];
    const float* Q1w = (const float*)d_in[3];
    const float* K2w = (const float*)d_in[4];
    const float* K2b = (const float*)d_in[5];
    const float* Q2w = (const float*)d_in[6];
    const float* Vw  = (const float*)d_in[7];
    const float* lq1 = (const float*)d_in[8];
    const float* lk1 = (const float*)d_in[9];
    const float* lq2 = (const float*)d_in[10];
    const float* lk2 = (const float*)d_in[11];
    const float* gnw = (const float*)d_in[12];
    const float* gnb = (const float*)d_in[13];
    const float* Ow  = (const float*)d_in[14];
    const float* Ob  = (const float*)d_in[15];

    const size_t SZ = (size_t)2 * 8 * 2048 * 64;   // 2M elements per tensor
    bf16* q1 = (bf16*)d_ws;
    bf16* k1 = q1 + SZ;
    bf16* q2 = k1 + SZ;
    bf16* k2 = q2 + SZ;
    bf16* vt = k2 + SZ;
    float* stats = (float*)(vt + SZ);

    bf16* o  = (bf16*)d_out;   // scratch in d_out; fully overwritten by out_gemm
    bf16* xn = q1;             // q1 slot dead after attn_kernel

    hipMemsetAsync(stats, 0, 16 * sizeof(float), stream);

    proj_kernel<<<640, 256, 0, stream>>>(x, Q1w, K1w, Q2w, K2w, Vw, K1b, K2b,
                                         q1, k1, q2, k2, vt);
    attn_kernel<<<2048, 256, 0, stream>>>(q1, k1, q2, k2, vt,
                                          lq1, lk1, lq2, lk2, o);
    gn_stats_kernel<<<128, 256, 0, stream>>>(o, stats);
    gn_apply_kernel<<<1024, 256, 0, stream>>>(o, stats, gnw, gnb, xn);
    out_gemm_kernel<<<256, 256, 0, stream>>>(xn, Ow, Ob, (float*)d_out);
}

// Round 6
// 396.432 us; speedup vs baseline: 1.0102x; 1.0102x over previous
//
#include <hip/hip_runtime.h>
#include <hip/hip_bf16.h>

typedef __bf16 bf16;
typedef __attribute__((ext_vector_type(8))) __bf16 bf16x8;
typedef __attribute__((ext_vector_type(4))) float f32x4;

#define MFMA16(a, b, c) __builtin_amdgcn_mfma_f32_16x16x32_bf16((a), (b), (c), 0, 0, 0)

// B=2, S=2048, D=512, H=8, hd=64, G=4. All I/O float32; bf16 MFMA compute.
static constexpr float EPS = 1e-5f;
static constexpr float LAMBDA_INIT = 0.2f;

// Load 8 consecutive f32 (32B, 16B-aligned) and convert to bf16x8.
__device__ __forceinline__ bf16x8 cvt8(const float* p) {
    const f32x4 a = *(const f32x4*)p;
    const f32x4 b = *(const f32x4*)(p + 4);
    bf16x8 r;
    r[0] = (bf16)a[0]; r[1] = (bf16)a[1]; r[2] = (bf16)a[2]; r[3] = (bf16)a[3];
    r[4] = (bf16)b[0]; r[5] = (bf16)b[1]; r[6] = (bf16)b[2]; r[7] = (bf16)b[3];
    return r;
}

// ---------------------------------------------------------------------------
// Kernel 1: fused QKV projection GEMM (f32 in -> bf16 out).
// V^T rows are stored with a period-32 key permutation so that attention's
// P^T (exp of S^T in C-layout) is directly the PV B-operand in-lane:
//   position p = 8*quad + j  <->  key s5 = 4*quad + j (+12 if j>=4)
// ---------------------------------------------------------------------------
__global__ __launch_bounds__(256) void proj_kernel(
    const float* __restrict__ x,
    const float* __restrict__ q1w, const float* __restrict__ k1w,
    const float* __restrict__ q2w, const float* __restrict__ k2w,
    const float* __restrict__ vw,
    const float* __restrict__ k1b, const float* __restrict__ k2b,
    bf16* __restrict__ q1o, bf16* __restrict__ k1o,
    bf16* __restrict__ q2o, bf16* __restrict__ k2o,
    bf16* __restrict__ vto)
{
    const int lane = threadIdx.x & 63;
    const int wave = threadIdx.x >> 6;
    const int l15 = lane & 15, quad = lane >> 4;

    const int tile = blockIdx.x * 4 + wave;      // 64 m-tiles x 40 n-tiles
    const int mt = tile / 40;
    const int nt = tile % 40;
    const int wsel = nt >> 3;
    const int nb = (nt & 7) * 64;

    const float* W = (wsel == 0) ? q1w : (wsel == 1) ? k1w :
                     (wsel == 2) ? q2w : (wsel == 3) ? k2w : vw;

    const float* ap[4];
    const float* bp[4];
#pragma unroll
    for (int i = 0; i < 4; ++i)
        ap[i] = x + (size_t)(mt * 64 + i * 16 + l15) * 512 + quad * 8;
#pragma unroll
    for (int j = 0; j < 4; ++j)
        bp[j] = W + (size_t)(nb + j * 16 + l15) * 512 + quad * 8;

    f32x4 acc[4][4];
#pragma unroll
    for (int i = 0; i < 4; ++i)
#pragma unroll
        for (int j = 0; j < 4; ++j)
            acc[i][j] = (f32x4){0.f, 0.f, 0.f, 0.f};

    for (int kk = 0; kk < 16; ++kk) {
        bf16x8 af[4], bfr[4];
#pragma unroll
        for (int i = 0; i < 4; ++i) af[i] = cvt8(ap[i] + kk * 32);
#pragma unroll
        for (int j = 0; j < 4; ++j) bfr[j] = cvt8(bp[j] + kk * 32);
#pragma unroll
        for (int i = 0; i < 4; ++i)
#pragma unroll
            for (int j = 0; j < 4; ++j)
                acc[i][j] = MFMA16(af[i], bfr[j], acc[i][j]);
    }

    const float scale = (wsel == 0 || wsel == 2) ? 0.125f : 1.0f;
#pragma unroll
    for (int j = 0; j < 4; ++j) {
        const int ncol = nb + j * 16 + l15;
        float bias = 0.f;
        if (wsel == 1) bias = k1b[ncol];
        if (wsel == 3) bias = k2b[ncol];
        const int h = ncol >> 6, hd = ncol & 63;
#pragma unroll
        for (int i = 0; i < 4; ++i) {
#pragma unroll
            for (int r = 0; r < 4; ++r) {
                const int m = mt * 64 + i * 16 + quad * 4 + r;
                const int bidx = m >> 11, s = m & 2047;
                const float v = acc[i][j][r] * scale + bias;
                if (wsel == 4) {
                    // permuted V^T store (see header comment)
                    const int s5 = s & 31;
                    const int p = ((s5 & 15) >> 2) * 8 + (s5 & 3) + ((s5 >> 4) << 2);
                    const int sp = (s & ~31) | p;
                    vto[((size_t)(bidx * 8 + h) * 64 + hd) * 2048 + sp] = (bf16)v;
                } else {
                    bf16* dst = (wsel == 0) ? q1o : (wsel == 1) ? k1o :
                                (wsel == 2) ? q2o : k2o;
                    dst[((size_t)(bidx * 8 + h) * 2048 + s) * 64 + hd] = (bf16)v;
                }
            }
        }
    }
}

// ---------------------------------------------------------------------------
// Kernel 2: dual-stream flash attention, transposed (S^T / O^T) formulation.
// No LDS / cross-lane ops in the main loop: S^T = MFMA(Kfrag, Qfrag); exp'd
// scores packed in-lane are directly the PV B-operand (keys permuted in vt);
// O^T = MFMA(V^Tfrag, P^Tfrag). K-split: block = 4 waves on one 16-query
// tile, wave w covers keys [w*512, (w+1)*512); no-max softmax => partial
// (O,l) sum across waves in a 3-barrier epilogue. Grid = B*H*128.
// ---------------------------------------------------------------------------
__global__ __launch_bounds__(256) void attn_kernel(
    const bf16* __restrict__ q1, const bf16* __restrict__ k1,
    const bf16* __restrict__ q2, const bf16* __restrict__ k2,
    const bf16* __restrict__ vt,
    const float* __restrict__ lq1, const float* __restrict__ lk1,
    const float* __restrict__ lq2, const float* __restrict__ lk2,
    bf16* __restrict__ o)
{
    __shared__ __align__(16) f32x4 rbuf[2][8][64];     // pairwise O-reduce (16 KB)
    __shared__ float lbuf[4][2][16];                   // per-wave l sums (512 B)

    const int lane = threadIdx.x & 63;
    const int wave = threadIdx.x >> 6;
    const int l15 = lane & 15, quad = lane >> 4;

    const int bh = blockIdx.x >> 7;      // 0..15
    const int qt = blockIdx.x & 127;     // 16-query tile
    const int b = bh >> 3, h = bh & 7;
    const int qbase = qt * 16;

    // Q fragments (B-operand: lane = query, holds d-chunk quad*8..+7)
    const bf16* q1p = q1 + ((size_t)bh * 2048 + qbase + l15) * 64 + quad * 8;
    const bf16* q2p = q2 + ((size_t)bh * 2048 + qbase + l15) * 64 + quad * 8;
    const bf16x8 q1f0 = *(const bf16x8*)(q1p);
    const bf16x8 q1f1 = *(const bf16x8*)(q1p + 32);
    const bf16x8 q2f0 = *(const bf16x8*)(q2p);
    const bf16x8 q2f1 = *(const bf16x8*)(q2p + 32);

    const bf16* k1base = k1 + (size_t)bh * 2048 * 64;
    const bf16* k2base = k2 + (size_t)bh * 2048 * 64;
    const bf16* vbase  = vt + (size_t)bh * 64 * 2048;

    f32x4 O1[4], O2[4];
    float l1 = 0.f, l2 = 0.f;            // per-lane: query = l15
#pragma unroll
    for (int t = 0; t < 4; ++t) {
        O1[t] = (f32x4){0.f, 0.f, 0.f, 0.f};
        O2[t] = (f32x4){0.f, 0.f, 0.f, 0.f};
    }

    const int kb0 = wave * 16;           // this wave's 16 key-blocks of 32
    for (int it = 0; it < 16; ++it) {
        const int kbase = (kb0 + it) * 32;

        // K fragments (A-operand: lane = key, holds d-chunk quad*8..+7)
        const bf16* k1p = k1base + (size_t)(kbase + l15) * 64 + quad * 8;
        const bf16x8 k1t0a = *(const bf16x8*)(k1p);
        const bf16x8 k1t0b = *(const bf16x8*)(k1p + 32);
        const bf16x8 k1t1a = *(const bf16x8*)(k1p + 16 * 64);
        const bf16x8 k1t1b = *(const bf16x8*)(k1p + 16 * 64 + 32);

        const bf16* k2p = k2base + (size_t)(kbase + l15) * 64 + quad * 8;
        const bf16x8 k2t0a = *(const bf16x8*)(k2p);
        const bf16x8 k2t0b = *(const bf16x8*)(k2p + 32);
        const bf16x8 k2t1a = *(const bf16x8*)(k2p + 16 * 64);
        const bf16x8 k2t1b = *(const bf16x8*)(k2p + 16 * 64 + 32);

        // V^T fragments (A-operand: lane = d, holds permuted keys quad*8..+7)
        const bf16* vp = vbase + (size_t)l15 * 2048 + kbase + quad * 8;
        const bf16x8 v0 = *(const bf16x8*)(vp);
        const bf16x8 v1 = *(const bf16x8*)(vp + 16 * 2048);
        const bf16x8 v2 = *(const bf16x8*)(vp + 32 * 2048);
        const bf16x8 v3 = *(const bf16x8*)(vp + 48 * 2048);

        // S^T tiles: rows = keys (quad*4+r), cols = queries (l15)
        f32x4 z = (f32x4){0.f, 0.f, 0.f, 0.f};
        f32x4 s1t0 = MFMA16(k1t0a, q1f0, z);  s1t0 = MFMA16(k1t0b, q1f1, s1t0);
        f32x4 s1t1 = MFMA16(k1t1a, q1f0, z);  s1t1 = MFMA16(k1t1b, q1f1, s1t1);
        f32x4 s2t0 = MFMA16(k2t0a, q2f0, z);  s2t0 = MFMA16(k2t0b, q2f1, s2t0);
        f32x4 s2t1 = MFMA16(k2t1a, q2f0, z);  s2t1 = MFMA16(k2t1b, q2f1, s2t1);

        // exp + in-lane pack straight into PV B-operand layout:
        // frag[j]   (j<4)  = tile0 reg j   (key 4*quad + j)
        // frag[4+j]        = tile1 reg j   (key 16 + 4*quad + j)
        bf16x8 b1, b2;
#pragma unroll
        for (int r = 0; r < 4; ++r) {
            float e;
            e = __expf(s1t0[r]); l1 += e; b1[r]     = (bf16)e;
            e = __expf(s1t1[r]); l1 += e; b1[4 + r] = (bf16)e;
            e = __expf(s2t0[r]); l2 += e; b2[r]     = (bf16)e;
            e = __expf(s2t1[r]); l2 += e; b2[4 + r] = (bf16)e;
        }

        // O^T += V^T * P^T  (rows = d, cols = queries)
        O1[0] = MFMA16(v0, b1, O1[0]);
        O1[1] = MFMA16(v1, b1, O1[1]);
        O1[2] = MFMA16(v2, b1, O1[2]);
        O1[3] = MFMA16(v3, b1, O1[3]);
        O2[0] = MFMA16(v0, b2, O2[0]);
        O2[1] = MFMA16(v1, b2, O2[1]);
        O2[2] = MFMA16(v2, b2, O2[2]);
        O2[3] = MFMA16(v3, b2, O2[3]);
    }

    // Per-wave l: sum over the 4 quads holding this query's keys.
    l1 += __shfl_xor(l1, 16, 64);  l1 += __shfl_xor(l1, 32, 64);
    l2 += __shfl_xor(l2, 16, 64);  l2 += __shfl_xor(l2, 32, 64);
    if (lane < 16) {
        lbuf[wave][0][lane] = l1;
        lbuf[wave][1][lane] = l2;
    }

    // Pairwise cross-wave O reduction: (0+=1, 2+=3), then (0+=2).
    if (wave == 1 || wave == 3) {
        const int widx = wave >> 1;
#pragma unroll
        for (int t = 0; t < 4; ++t) {
            rbuf[widx][t][lane]     = O1[t];
            rbuf[widx][t + 4][lane] = O2[t];
        }
    }
    __syncthreads();
    if (wave == 0 || wave == 2) {
        const int widx = wave >> 1;
#pragma unroll
        for (int t = 0; t < 4; ++t) {
            O1[t] += rbuf[widx][t][lane];
            O2[t] += rbuf[widx][t + 4][lane];
        }
    }
    __syncthreads();
    if (wave == 2) {
#pragma unroll
        for (int t = 0; t < 4; ++t) {
            rbuf[0][t][lane]     = O1[t];
            rbuf[0][t + 4][lane] = O2[t];
        }
    }
    __syncthreads();
    if (wave == 0) {
#pragma unroll
        for (int t = 0; t < 4; ++t) {
            O1[t] += rbuf[0][t][lane];
            O2[t] += rbuf[0][t + 4][lane];
        }
        const float L1 = lbuf[0][0][l15] + lbuf[1][0][l15] + lbuf[2][0][l15] + lbuf[3][0][l15];
        const float L2 = lbuf[0][1][l15] + lbuf[1][1][l15] + lbuf[2][1][l15] + lbuf[3][1][l15];
        const float lam = __expf(lq1[h] * lk1[h]) - __expf(lq2[h] * lk2[h]) + LAMBDA_INIT;
        const float inv1 = 1.f / L1;
        const float inv2 = lam / L2;
        const size_t row = (size_t)(b * 2048 + qbase + l15) * 512 + h * 64;
#pragma unroll
        for (int t = 0; t < 4; ++t) {
#pragma unroll
            for (int r = 0; r < 4; ++r) {
                const float val = O1[t][r] * inv1 - O2[t][r] * inv2;
                o[row + t * 16 + quad * 4 + r] = (bf16)val;   // d = 16t + 4*quad + r
            }
        }
    }
}

// ---------------------------------------------------------------------------
// Kernel 3: GroupNorm stats over (128 channels x 2048 s) per (b,g). [unchanged]
// ---------------------------------------------------------------------------
__global__ __launch_bounds__(256) void gn_stats_kernel(
    const bf16* __restrict__ o, float* __restrict__ stats)
{
    const int bg = blockIdx.x >> 4;
    const int chunk = blockIdx.x & 15;
    const int b = bg >> 2, g = bg & 3;

    float sum = 0.f, sumsq = 0.f;
    for (int i = threadIdx.x; i < 128 * 128; i += 256) {
        const int sr = i >> 7, c = i & 127;
        const float v = (float)o[((size_t)(b * 2048 + chunk * 128 + sr) * 512) + g * 128 + c];
        sum += v; sumsq += v * v;
    }
#pragma unroll
    for (int off = 1; off < 64; off <<= 1) {
        sum += __shfl_xor(sum, off, 64);
        sumsq += __shfl_xor(sumsq, off, 64);
    }
    __shared__ float red[2][4];
    const int wave = threadIdx.x >> 6, lane = threadIdx.x & 63;
    if (lane == 0) { red[0][wave] = sum; red[1][wave] = sumsq; }
    __syncthreads();
    if (threadIdx.x == 0) {
        float s0 = 0.f, s1 = 0.f;
        for (int w = 0; w < 4; ++w) { s0 += red[0][w]; s1 += red[1][w]; }
        atomicAdd(&stats[bg * 2], s0);
        atomicAdd(&stats[bg * 2 + 1], s1);
    }
}

// ---------------------------------------------------------------------------
// Kernel 4: apply GroupNorm affine -> xn (bf16). [unchanged]
// ---------------------------------------------------------------------------
__global__ __launch_bounds__(256) void gn_apply_kernel(
    const bf16* __restrict__ o, const float* __restrict__ stats,
    const float* __restrict__ gnw, const float* __restrict__ gnb,
    bf16* __restrict__ xn)
{
    const int idx = blockIdx.x * 256 + threadIdx.x;
    const int base = idx * 8;
    const int c = base & 511;
    const int b = base >> 20;
    const int g = c >> 7;
    const int bg = b * 4 + g;

    const float N = 128.f * 2048.f;
    const float mu = stats[bg * 2] / N;
    const float var = stats[bg * 2 + 1] / N - mu * mu;
    const float rstd = rsqrtf(var + EPS);

    const bf16x8 vals = *(const bf16x8*)(o + base);
    bf16x8 out;
#pragma unroll
    for (int j = 0; j < 8; ++j) {
        const float w = gnw[c + j];
        const float bb = gnb[c + j];
        out[j] = (bf16)(((float)vals[j] - mu) * rstd * w + bb);
    }
    *(bf16x8*)(xn + base) = out;
}

// ---------------------------------------------------------------------------
// Kernel 5: output GEMM y = xn @ out_w^T + out_b, y f32. [unchanged]
// ---------------------------------------------------------------------------
__global__ __launch_bounds__(256) void out_gemm_kernel(
    const bf16* __restrict__ xn, const float* __restrict__ ow,
    const float* __restrict__ ob, float* __restrict__ y)
{
    const int lane = threadIdx.x & 63;
    const int wave = threadIdx.x >> 6;
    const int l15 = lane & 15, quad = lane >> 4;

    const int tile = blockIdx.x * 4 + wave;
    const int mt = tile >> 4;
    const int nt = tile & 15;

    const bf16* ap[4];
#pragma unroll
    for (int i = 0; i < 4; ++i)
        ap[i] = xn + (size_t)(mt * 64 + i * 16 + l15) * 512 + quad * 8;
    const float* bp[2];
#pragma unroll
    for (int j = 0; j < 2; ++j)
        bp[j] = ow + (size_t)(nt * 32 + j * 16 + l15) * 512 + quad * 8;

    f32x4 acc[4][2];
#pragma unroll
    for (int i = 0; i < 4; ++i)
#pragma unroll
        for (int j = 0; j < 2; ++j)
            acc[i][j] = (f32x4){0.f, 0.f, 0.f, 0.f};

    for (int kk = 0; kk < 16; ++kk) {
        bf16x8 af[4], bfr[2];
#pragma unroll
        for (int i = 0; i < 4; ++i) af[i] = *(const bf16x8*)(ap[i] + kk * 32);
#pragma unroll
        for (int j = 0; j < 2; ++j) bfr[j] = cvt8(bp[j] + kk * 32);
#pragma unroll
        for (int i = 0; i < 4; ++i)
#pragma unroll
            for (int j = 0; j < 2; ++j)
                acc[i][j] = MFMA16(af[i], bfr[j], acc[i][j]);
    }

#pragma unroll
    for (int j = 0; j < 2; ++j) {
        const int ncol = nt * 32 + j * 16 + l15;
        const float bias = ob[ncol];
#pragma unroll
        for (int i = 0; i < 4; ++i) {
#pragma unroll
            for (int r = 0; r < 4; ++r) {
                const int m = mt * 64 + i * 16 + quad * 4 + r;
                y[(size_t)m * 512 + ncol] = acc[i][j][r] + bias;
            }
        }
    }
}

// ---------------------------------------------------------------------------
extern "C" void kernel_launch(void* const* d_in, const int* in_sizes, int n_in,
                              void* d_out, int out_size, void* d_ws, size_t ws_size,
                              hipStream_t stream)
{
    const float* x   = (const float*)d_in[0];
    const float* K1w = (const float*)d_in[1];
    const float* K1b = (const float*)d_in[2];
    const float* Q1w = (const float*)d_in[3];
    const float* K2w = (const float*)d_in[4];
    const float* K2b = (const float*)d_in[5];
    const float* Q2w = (const float*)d_in[6];
    const float* Vw  = (const float*)d_in[7];
    const float* lq1 = (const float*)d_in[8];
    const float* lk1 = (const float*)d_in[9];
    const float* lq2 = (const float*)d_in[10];
    const float* lk2 = (const float*)d_in[11];
    const float* gnw = (const float*)d_in[12];
    const float* gnb = (const float*)d_in[13];
    const float* Ow  = (const float*)d_in[14];
    const float* Ob  = (const float*)d_in[15];

    const size_t SZ = (size_t)2 * 8 * 2048 * 64;   // 2M elements per tensor
    bf16* q1 = (bf16*)d_ws;
    bf16* k1 = q1 + SZ;
    bf16* q2 = k1 + SZ;
    bf16* k2 = q2 + SZ;
    bf16* vt = k2 + SZ;
    float* stats = (float*)(vt + SZ);

    bf16* o  = (bf16*)d_out;   // scratch in d_out; fully overwritten by out_gemm
    bf16* xn = q1;             // q1 slot dead after attn_kernel

    hipMemsetAsync(stats, 0, 16 * sizeof(float), stream);

    proj_kernel<<<640, 256, 0, stream>>>(x, Q1w, K1w, Q2w, K2w, Vw, K1b, K2b,
                                         q1, k1, q2, k2, vt);
    attn_kernel<<<2048, 256, 0, stream>>>(q1, k1, q2, k2, vt,
                                          lq1, lk1, lq2, lk2, o);
    gn_stats_kernel<<<128, 256, 0, stream>>>(o, stats);
    gn_apply_kernel<<<1024, 256, 0, stream>>>(o, stats, gnw, gnb, xn);
    out_gemm_kernel<<<256, 256, 0, stream>>>(xn, Ow, Ob, (float*)d_out);
}

// Round 7
// 271.173 us; speedup vs baseline: 1.4768x; 1.4619x over previous
//
#include <hip/hip_runtime.h>
#include <hip/hip_bf16.h>

typedef __bf16 bf16;
typedef __attribute__((ext_vector_type(8))) __bf16 bf16x8;
typedef __attribute__((ext_vector_type(4))) float f32x4;

#define MFMA16(a, b, c) __builtin_amdgcn_mfma_f32_16x16x32_bf16((a), (b), (c), 0, 0, 0)

// B=2, S=2048, D=512, H=8, hd=64, G=4. All I/O float32; bf16 MFMA compute.
static constexpr float EPS = 1e-5f;
static constexpr float LAMBDA_INIT = 0.2f;

// Load 8 consecutive f32 (32B, 16B-aligned) and convert to bf16x8.
__device__ __forceinline__ bf16x8 cvt8(const float* p) {
    const f32x4 a = *(const f32x4*)p;
    const f32x4 b = *(const f32x4*)(p + 4);
    bf16x8 r;
    r[0] = (bf16)a[0]; r[1] = (bf16)a[1]; r[2] = (bf16)a[2]; r[3] = (bf16)a[3];
    r[4] = (bf16)b[0]; r[5] = (bf16)b[1]; r[6] = (bf16)b[2]; r[7] = (bf16)b[3];
    return r;
}

// Async 16B global -> LDS (lane i lands at lds_base + i*16; base wave-uniform).
__device__ __forceinline__ void gload_lds16(const void* g, void* l) {
    __builtin_amdgcn_global_load_lds(
        (const __attribute__((address_space(1))) unsigned int*)g,
        (__attribute__((address_space(3))) unsigned int*)l,
        16, 0, 0);
}

// ---------------------------------------------------------------------------
// Kernel 1: fused QKV projection GEMM (f32 in -> bf16 out).
// V^T rows stored with a period-32 key permutation so attention's P^T
// (exp of S^T C-layout) is directly the PV B-operand in-lane.
// ---------------------------------------------------------------------------
__global__ __launch_bounds__(256) void proj_kernel(
    const float* __restrict__ x,
    const float* __restrict__ q1w, const float* __restrict__ k1w,
    const float* __restrict__ q2w, const float* __restrict__ k2w,
    const float* __restrict__ vw,
    const float* __restrict__ k1b, const float* __restrict__ k2b,
    bf16* __restrict__ q1o, bf16* __restrict__ k1o,
    bf16* __restrict__ q2o, bf16* __restrict__ k2o,
    bf16* __restrict__ vto)
{
    const int lane = threadIdx.x & 63;
    const int wave = threadIdx.x >> 6;
    const int l15 = lane & 15, quad = lane >> 4;

    const int tile = blockIdx.x * 4 + wave;      // 64 m-tiles x 40 n-tiles
    const int mt = tile / 40;
    const int nt = tile % 40;
    const int wsel = nt >> 3;
    const int nb = (nt & 7) * 64;

    const float* W = (wsel == 0) ? q1w : (wsel == 1) ? k1w :
                     (wsel == 2) ? q2w : (wsel == 3) ? k2w : vw;

    const float* ap[4];
    const float* bp[4];
#pragma unroll
    for (int i = 0; i < 4; ++i)
        ap[i] = x + (size_t)(mt * 64 + i * 16 + l15) * 512 + quad * 8;
#pragma unroll
    for (int j = 0; j < 4; ++j)
        bp[j] = W + (size_t)(nb + j * 16 + l15) * 512 + quad * 8;

    f32x4 acc[4][4];
#pragma unroll
    for (int i = 0; i < 4; ++i)
#pragma unroll
        for (int j = 0; j < 4; ++j)
            acc[i][j] = (f32x4){0.f, 0.f, 0.f, 0.f};

    for (int kk = 0; kk < 16; ++kk) {
        bf16x8 af[4], bfr[4];
#pragma unroll
        for (int i = 0; i < 4; ++i) af[i] = cvt8(ap[i] + kk * 32);
#pragma unroll
        for (int j = 0; j < 4; ++j) bfr[j] = cvt8(bp[j] + kk * 32);
#pragma unroll
        for (int i = 0; i < 4; ++i)
#pragma unroll
            for (int j = 0; j < 4; ++j)
                acc[i][j] = MFMA16(af[i], bfr[j], acc[i][j]);
    }

    const float scale = (wsel == 0 || wsel == 2) ? 0.125f : 1.0f;
#pragma unroll
    for (int j = 0; j < 4; ++j) {
        const int ncol = nb + j * 16 + l15;
        float bias = 0.f;
        if (wsel == 1) bias = k1b[ncol];
        if (wsel == 3) bias = k2b[ncol];
        const int h = ncol >> 6, hd = ncol & 63;
#pragma unroll
        for (int i = 0; i < 4; ++i) {
#pragma unroll
            for (int r = 0; r < 4; ++r) {
                const int m = mt * 64 + i * 16 + quad * 4 + r;
                const int bidx = m >> 11, s = m & 2047;
                const float v = acc[i][j][r] * scale + bias;
                if (wsel == 4) {
                    // permuted V^T store
                    const int s5 = s & 31;
                    const int p = ((s5 & 15) >> 2) * 8 + (s5 & 3) + ((s5 >> 4) << 2);
                    const int sp = (s & ~31) | p;
                    vto[((size_t)(bidx * 8 + h) * 64 + hd) * 2048 + sp] = (bf16)v;
                } else {
                    bf16* dst = (wsel == 0) ? q1o : (wsel == 1) ? k1o :
                                (wsel == 2) ? q2o : k2o;
                    dst[((size_t)(bidx * 8 + h) * 2048 + s) * 64 + hd] = (bf16)v;
                }
            }
        }
    }
}

// ---------------------------------------------------------------------------
// Kernel 2: dual-stream flash attention, transposed formulation, LDS-shared
// K/V. Block = 8 waves / 64 queries: wave w -> q-tile (w&3), key-half (w>>2).
// Per iter: stage K1/K2/V tiles for both key halves (24 KB) via
// global_load_lds(16B); 2-barrier m97 loop; frag math = round-6 (verified).
// Partial (O,l) summed across wave pairs in a 4-barrier LDS epilogue.
// Grid = B*H*32 = 512 blocks.
// ---------------------------------------------------------------------------
__global__ __launch_bounds__(512, 4) void attn_kernel(
    const bf16* __restrict__ q1, const bf16* __restrict__ k1,
    const bf16* __restrict__ q2, const bf16* __restrict__ k2,
    const bf16* __restrict__ vt,
    const float* __restrict__ lq1, const float* __restrict__ lk1,
    const float* __restrict__ lq2, const float* __restrict__ lk2,
    bf16* __restrict__ o)
{
    __shared__ __align__(16) bf16 smem[12288];   // 24 KB: K1 | K2 | V (2 halves each)
    __shared__ float lbuf[8][2][16];

    const int tid = threadIdx.x;
    const int wave = tid >> 6;
    const int lane = tid & 63;
    const int l15 = lane & 15, quad = lane >> 4;
    const int qtile = wave & 3;          // q-tile within block
    const int kg = wave >> 2;            // key half for compute

    const int bh = blockIdx.x >> 5;      // 0..15
    const int qt = blockIdx.x & 31;      // 64-query block
    const int b = bh >> 3, h = bh & 7;

    const bf16* k1t = k1 + (size_t)bh * 2048 * 64;
    const bf16* k2t = k2 + (size_t)bh * 2048 * 64;
    const bf16* vtt = vt + (size_t)bh * 64 * 2048;

    // Q fragments (B-operand: lane = query, d-chunk quad*8..+7)
    const int qrow = qt * 64 + qtile * 16 + l15;
    const bf16* q1p = q1 + ((size_t)bh * 2048 + qrow) * 64 + quad * 8;
    const bf16* q2p = q2 + ((size_t)bh * 2048 + qrow) * 64 + quad * 8;
    const bf16x8 q1f0 = *(const bf16x8*)(q1p);
    const bf16x8 q1f1 = *(const bf16x8*)(q1p + 32);
    const bf16x8 q2f0 = *(const bf16x8*)(q2p);
    const bf16x8 q2f1 = *(const bf16x8*)(q2p + 32);

    // Staging: wave w stages 1 KB per tensor per iter.
    const int sw = wave & 3;                       // sub-chunk
    const int skey0 = (wave < 4) ? 0 : 1024;       // which key half it stages
    bf16* k1dst = smem + wave * 512;
    bf16* k2dst = smem + 4096 + wave * 512;
    bf16* vdst  = smem + 8192 + wave * 512;
    const size_t ksrc0 = (size_t)skey0 * 64 + sw * 512 + lane * 8;
    const size_t vsrc0 = (size_t)(sw * 16 + (lane >> 2)) * 2048 + skey0 + (lane & 3) * 8;

    // Compute-side LDS tile bases for this wave's key half.
    const bf16* k1r = smem + kg * 2048;            // 32 keys x 64 d
    const bf16* k2r = smem + 4096 + kg * 2048;
    const bf16* vr  = smem + 8192 + kg * 2048;     // 64 d x 32 keys (permuted)

    f32x4 O1[4], O2[4];
    float l1 = 0.f, l2 = 0.f;                      // per-lane: query = l15
#pragma unroll
    for (int t = 0; t < 4; ++t) {
        O1[t] = (f32x4){0.f, 0.f, 0.f, 0.f};
        O2[t] = (f32x4){0.f, 0.f, 0.f, 0.f};
    }

    for (int it = 0; it < 32; ++it) {
        const size_t koff = ksrc0 + (size_t)it * 32 * 64;
        gload_lds16(k1t + koff, k1dst);
        gload_lds16(k2t + koff, k2dst);
        gload_lds16(vtt + vsrc0 + it * 32, vdst);
        __syncthreads();   // drains vmcnt: staged data visible

        const bf16x8 k1t0a = *(const bf16x8*)(k1r + l15 * 64 + quad * 8);
        const bf16x8 k1t0b = *(const bf16x8*)(k1r + l15 * 64 + 32 + quad * 8);
        const bf16x8 k1t1a = *(const bf16x8*)(k1r + (16 + l15) * 64 + quad * 8);
        const bf16x8 k1t1b = *(const bf16x8*)(k1r + (16 + l15) * 64 + 32 + quad * 8);
        const bf16x8 k2t0a = *(const bf16x8*)(k2r + l15 * 64 + quad * 8);
        const bf16x8 k2t0b = *(const bf16x8*)(k2r + l15 * 64 + 32 + quad * 8);
        const bf16x8 k2t1a = *(const bf16x8*)(k2r + (16 + l15) * 64 + quad * 8);
        const bf16x8 k2t1b = *(const bf16x8*)(k2r + (16 + l15) * 64 + 32 + quad * 8);
        const bf16x8 v0 = *(const bf16x8*)(vr + l15 * 32 + quad * 8);
        const bf16x8 v1 = *(const bf16x8*)(vr + (16 + l15) * 32 + quad * 8);
        const bf16x8 v2 = *(const bf16x8*)(vr + (32 + l15) * 32 + quad * 8);
        const bf16x8 v3 = *(const bf16x8*)(vr + (48 + l15) * 32 + quad * 8);

        // S^T tiles: rows = keys (quad*4+r), cols = queries (l15)
        f32x4 z = (f32x4){0.f, 0.f, 0.f, 0.f};
        f32x4 s1t0 = MFMA16(k1t0a, q1f0, z);  s1t0 = MFMA16(k1t0b, q1f1, s1t0);
        f32x4 s1t1 = MFMA16(k1t1a, q1f0, z);  s1t1 = MFMA16(k1t1b, q1f1, s1t1);
        f32x4 s2t0 = MFMA16(k2t0a, q2f0, z);  s2t0 = MFMA16(k2t0b, q2f1, s2t0);
        f32x4 s2t1 = MFMA16(k2t1a, q2f0, z);  s2t1 = MFMA16(k2t1b, q2f1, s2t1);

        // exp + in-lane pack into PV B-operand (keys permuted in vt)
        bf16x8 b1, b2;
#pragma unroll
        for (int r = 0; r < 4; ++r) {
            float e;
            e = __expf(s1t0[r]); l1 += e; b1[r]     = (bf16)e;
            e = __expf(s1t1[r]); l1 += e; b1[4 + r] = (bf16)e;
            e = __expf(s2t0[r]); l2 += e; b2[r]     = (bf16)e;
            e = __expf(s2t1[r]); l2 += e; b2[4 + r] = (bf16)e;
        }

        // O^T += V^T * P^T
        O1[0] = MFMA16(v0, b1, O1[0]);
        O1[1] = MFMA16(v1, b1, O1[1]);
        O1[2] = MFMA16(v2, b1, O1[2]);
        O1[3] = MFMA16(v3, b1, O1[3]);
        O2[0] = MFMA16(v0, b2, O2[0]);
        O2[1] = MFMA16(v1, b2, O2[1]);
        O2[2] = MFMA16(v2, b2, O2[2]);
        O2[3] = MFMA16(v3, b2, O2[3]);

        __syncthreads();   // before next iter overwrites staging
    }

    // Per-wave l: sum over the 4 quads covering this query's keys.
    l1 += __shfl_xor(l1, 16, 64);  l1 += __shfl_xor(l1, 32, 64);
    l2 += __shfl_xor(l2, 16, 64);  l2 += __shfl_xor(l2, 32, 64);
    if (lane < 16) {
        lbuf[wave][0][lane] = l1;
        lbuf[wave][1][lane] = l2;
    }
    __syncthreads();   // loop reads done; lbuf visible; smem reusable

    // Cross-pair O reduction (wave w+4 -> wave w), staged through smem.
    f32x4* rb = (f32x4*)smem;          // 1536 f32x4 slots; use 1024
    if (wave == 4 || wave == 5) {
        f32x4* dst = rb + (wave - 4) * 512;
#pragma unroll
        for (int t = 0; t < 4; ++t) {
            dst[t * 64 + lane]       = O1[t];
            dst[(4 + t) * 64 + lane] = O2[t];
        }
    }
    __syncthreads();
    if (wave == 0 || wave == 1) {
        const f32x4* src = rb + wave * 512;
#pragma unroll
        for (int t = 0; t < 4; ++t) {
            O1[t] += src[t * 64 + lane];
            O2[t] += src[(4 + t) * 64 + lane];
        }
    }
    __syncthreads();
    if (wave == 6 || wave == 7) {
        f32x4* dst = rb + (wave - 6) * 512;
#pragma unroll
        for (int t = 0; t < 4; ++t) {
            dst[t * 64 + lane]       = O1[t];
            dst[(4 + t) * 64 + lane] = O2[t];
        }
    }
    __syncthreads();
    if (wave == 2 || wave == 3) {
        const f32x4* src = rb + (wave - 2) * 512;
#pragma unroll
        for (int t = 0; t < 4; ++t) {
            O1[t] += src[t * 64 + lane];
            O2[t] += src[(4 + t) * 64 + lane];
        }
    }

    if (wave < 4) {
        const float L1 = l1 + lbuf[wave + 4][0][l15];
        const float L2 = l2 + lbuf[wave + 4][1][l15];
        const float lam = __expf(lq1[h] * lk1[h]) - __expf(lq2[h] * lk2[h]) + LAMBDA_INIT;
        const float inv1 = 1.f / L1;
        const float inv2 = lam / L2;
        const size_t row = (size_t)(b * 2048 + qt * 64 + wave * 16 + l15) * 512 + h * 64;
#pragma unroll
        for (int t = 0; t < 4; ++t) {
#pragma unroll
            for (int r = 0; r < 4; ++r) {
                const float val = O1[t][r] * inv1 - O2[t][r] * inv2;
                o[row + t * 16 + quad * 4 + r] = (bf16)val;   // d = 16t + 4*quad + r
            }
        }
    }
}

// ---------------------------------------------------------------------------
// Kernel 3: GroupNorm stats over (128 channels x 2048 s) per (b,g). [unchanged]
// ---------------------------------------------------------------------------
__global__ __launch_bounds__(256) void gn_stats_kernel(
    const bf16* __restrict__ o, float* __restrict__ stats)
{
    const int bg = blockIdx.x >> 4;
    const int chunk = blockIdx.x & 15;
    const int b = bg >> 2, g = bg & 3;

    float sum = 0.f, sumsq = 0.f;
    for (int i = threadIdx.x; i < 128 * 128; i += 256) {
        const int sr = i >> 7, c = i & 127;
        const float v = (float)o[((size_t)(b * 2048 + chunk * 128 + sr) * 512) + g * 128 + c];
        sum += v; sumsq += v * v;
    }
#pragma unroll
    for (int off = 1; off < 64; off <<= 1) {
        sum += __shfl_xor(sum, off, 64);
        sumsq += __shfl_xor(sumsq, off, 64);
    }
    __shared__ float red[2][4];
    const int wave = threadIdx.x >> 6, lane = threadIdx.x & 63;
    if (lane == 0) { red[0][wave] = sum; red[1][wave] = sumsq; }
    __syncthreads();
    if (threadIdx.x == 0) {
        float s0 = 0.f, s1 = 0.f;
        for (int w = 0; w < 4; ++w) { s0 += red[0][w]; s1 += red[1][w]; }
        atomicAdd(&stats[bg * 2], s0);
        atomicAdd(&stats[bg * 2 + 1], s1);
    }
}

// ---------------------------------------------------------------------------
// Kernel 4: apply GroupNorm affine -> xn (bf16). [unchanged]
// ---------------------------------------------------------------------------
__global__ __launch_bounds__(256) void gn_apply_kernel(
    const bf16* __restrict__ o, const float* __restrict__ stats,
    const float* __restrict__ gnw, const float* __restrict__ gnb,
    bf16* __restrict__ xn)
{
    const int idx = blockIdx.x * 256 + threadIdx.x;
    const int base = idx * 8;
    const int c = base & 511;
    const int b = base >> 20;
    const int g = c >> 7;
    const int bg = b * 4 + g;

    const float N = 128.f * 2048.f;
    const float mu = stats[bg * 2] / N;
    const float var = stats[bg * 2 + 1] / N - mu * mu;
    const float rstd = rsqrtf(var + EPS);

    const bf16x8 vals = *(const bf16x8*)(o + base);
    bf16x8 out;
#pragma unroll
    for (int j = 0; j < 8; ++j) {
        const float w = gnw[c + j];
        const float bb = gnb[c + j];
        out[j] = (bf16)(((float)vals[j] - mu) * rstd * w + bb);
    }
    *(bf16x8*)(xn + base) = out;
}

// ---------------------------------------------------------------------------
// Kernel 5: output GEMM y = xn @ out_w^T + out_b, y f32. [unchanged]
// ---------------------------------------------------------------------------
__global__ __launch_bounds__(256) void out_gemm_kernel(
    const bf16* __restrict__ xn, const float* __restrict__ ow,
    const float* __restrict__ ob, float* __restrict__ y)
{
    const int lane = threadIdx.x & 63;
    const int wave = threadIdx.x >> 6;
    const int l15 = lane & 15, quad = lane >> 4;

    const int tile = blockIdx.x * 4 + wave;
    const int mt = tile >> 4;
    const int nt = tile & 15;

    const bf16* ap[4];
#pragma unroll
    for (int i = 0; i < 4; ++i)
        ap[i] = xn + (size_t)(mt * 64 + i * 16 + l15) * 512 + quad * 8;
    const float* bp[2];
#pragma unroll
    for (int j = 0; j < 2; ++j)
        bp[j] = ow + (size_t)(nt * 32 + j * 16 + l15) * 512 + quad * 8;

    f32x4 acc[4][2];
#pragma unroll
    for (int i = 0; i < 4; ++i)
#pragma unroll
        for (int j = 0; j < 2; ++j)
            acc[i][j] = (f32x4){0.f, 0.f, 0.f, 0.f};

    for (int kk = 0; kk < 16; ++kk) {
        bf16x8 af[4], bfr[2];
#pragma unroll
        for (int i = 0; i < 4; ++i) af[i] = *(const bf16x8*)(ap[i] + kk * 32);
#pragma unroll
        for (int j = 0; j < 2; ++j) bfr[j] = cvt8(bp[j] + kk * 32);
#pragma unroll
        for (int i = 0; i < 4; ++i)
#pragma unroll
            for (int j = 0; j < 2; ++j)
                acc[i][j] = MFMA16(af[i], bfr[j], acc[i][j]);
    }

#pragma unroll
    for (int j = 0; j < 2; ++j) {
        const int ncol = nt * 32 + j * 16 + l15;
        const float bias = ob[ncol];
#pragma unroll
        for (int i = 0; i < 4; ++i) {
#pragma unroll
            for (int r = 0; r < 4; ++r) {
                const int m = mt * 64 + i * 16 + quad * 4 + r;
                y[(size_t)m * 512 + ncol] = acc[i][j][r] + bias;
            }
        }
    }
}

// ---------------------------------------------------------------------------
extern "C" void kernel_launch(void* const* d_in, const int* in_sizes, int n_in,
                              void* d_out, int out_size, void* d_ws, size_t ws_size,
                              hipStream_t stream)
{
    const float* x   = (const float*)d_in[0];
    const float* K1w = (const float*)d_in[1];
    const float* K1b = (const float*)d_in[2];
    const float* Q1w = (const float*)d_in[3];
    const float* K2w = (const float*)d_in[4];
    const float* K2b = (const float*)d_in[5];
    const float* Q2w = (const float*)d_in[6];
    const float* Vw  = (const float*)d_in[7];
    const float* lq1 = (const float*)d_in[8];
    const float* lk1 = (const float*)d_in[9];
    const float* lq2 = (const float*)d_in[10];
    const float* lk2 = (const float*)d_in[11];
    const float* gnw = (const float*)d_in[12];
    const float* gnb = (const float*)d_in[13];
    const float* Ow  = (const float*)d_in[14];
    const float* Ob  = (const float*)d_in[15];

    const size_t SZ = (size_t)2 * 8 * 2048 * 64;   // 2M elements per tensor
    bf16* q1 = (bf16*)d_ws;
    bf16* k1 = q1 + SZ;
    bf16* q2 = k1 + SZ;
    bf16* k2 = q2 + SZ;
    bf16* vt = k2 + SZ;
    float* stats = (float*)(vt + SZ);

    bf16* o  = (bf16*)d_out;   // scratch in d_out; fully overwritten by out_gemm
    bf16* xn = q1;             // q1 slot dead after attn_kernel

    hipMemsetAsync(stats, 0, 16 * sizeof(float), stream);

    proj_kernel<<<640, 256, 0, stream>>>(x, Q1w, K1w, Q2w, K2w, Vw, K1b, K2b,
                                         q1, k1, q2, k2, vt);
    attn_kernel<<<512, 512, 0, stream>>>(q1, k1, q2, k2, vt,
                                         lq1, lk1, lq2, lk2, o);
    gn_stats_kernel<<<128, 256, 0, stream>>>(o, stats);
    gn_apply_kernel<<<1024, 256, 0, stream>>>(o, stats, gnw, gnb, xn);
    out_gemm_kernel<<<256, 256, 0, stream>>>(xn, Ow, Ob, (float*)d_out);
}

// Round 8
// 217.296 us; speedup vs baseline: 1.8429x; 1.2479x over previous
//
#include <hip/hip_runtime.h>
#include <hip/hip_bf16.h>

typedef __bf16 bf16;
typedef __attribute__((ext_vector_type(8))) __bf16 bf16x8;
typedef __attribute__((ext_vector_type(4))) float f32x4;

#define MFMA16(a, b, c) __builtin_amdgcn_mfma_f32_16x16x32_bf16((a), (b), (c), 0, 0, 0)

// B=2, S=2048, D=512, H=8, hd=64, G=4. All I/O float32; bf16 MFMA compute.
static constexpr float EPS = 1e-5f;
static constexpr float LAMBDA_INIT = 0.2f;

// Load 8 consecutive f32 (32B, 16B-aligned) and convert to bf16x8.
__device__ __forceinline__ bf16x8 cvt8(const float* p) {
    const f32x4 a = *(const f32x4*)p;
    const f32x4 b = *(const f32x4*)(p + 4);
    bf16x8 r;
    r[0] = (bf16)a[0]; r[1] = (bf16)a[1]; r[2] = (bf16)a[2]; r[3] = (bf16)a[3];
    r[4] = (bf16)b[0]; r[5] = (bf16)b[1]; r[6] = (bf16)b[2]; r[7] = (bf16)b[3];
    return r;
}

// Async 16B global -> LDS (lane i lands at lds_base + i*16; base wave-uniform).
__device__ __forceinline__ void gload_lds16(const void* g, void* l) {
    __builtin_amdgcn_global_load_lds(
        (const __attribute__((address_space(1))) unsigned int*)g,
        (__attribute__((address_space(3))) unsigned int*)l,
        16, 0, 0);
}

// ---------------------------------------------------------------------------
// Kernel 1: fused QKV projection GEMM (f32 in -> bf16 out), m97-style.
// C = X(4096x512) @ Wcat^T(2560x512). 128x128 block tile (4 waves x 64x64),
// BK=32 f32 staged via global_load_lds(16B) into 32 KB LDS; 2-barrier K-loop.
// Each 128-row N-chunk lies within ONE weight => wsel block-uniform.
// q1/q2 scaled 0.125; V^T stored with the period-32 key permutation so
// attention's P^T is directly the PV B-operand in-lane.
// ---------------------------------------------------------------------------
__global__ __launch_bounds__(256) void proj_kernel(
    const float* __restrict__ x,
    const float* __restrict__ q1w, const float* __restrict__ k1w,
    const float* __restrict__ q2w, const float* __restrict__ k2w,
    const float* __restrict__ vw,
    const float* __restrict__ k1b, const float* __restrict__ k2b,
    bf16* __restrict__ q1o, bf16* __restrict__ k1o,
    bf16* __restrict__ q2o, bf16* __restrict__ k2o,
    bf16* __restrict__ vto)
{
    __shared__ __align__(16) float As[128 * 32];   // 16 KB
    __shared__ __align__(16) float Bs[128 * 32];   // 16 KB

    const int tid = threadIdx.x;
    const int wave = tid >> 6, lane = tid & 63;
    const int l15 = lane & 15, quad = lane >> 4;
    const int wm = wave >> 1, wn = wave & 1;       // wave tile in 2x2 grid

    const int mb = blockIdx.x / 20;                // 32 m-blocks of 128 rows
    const int nb = blockIdx.x % 20;                // 20 n-blocks of 128 rows
    const int wsel = nb >> 2;                      // block-uniform weight select
    const int nrow0 = (nb & 3) * 128;              // row base within weight

    const float* W = (wsel == 0) ? q1w : (wsel == 1) ? k1w :
                     (wsel == 2) ? q2w : (wsel == 3) ? k2w : vw;

    // Staging: wave stages chunks [wave*4, wave*4+4) of 8 rows x 32 f32 each.
    const int srow = lane >> 3;                    // 0..7 row within chunk
    const int scol = (lane & 7) * 4;               // f32 col within 32
    const float* xg = x + (size_t)(mb * 128 + srow) * 512 + scol;
    const float* wg = W + (size_t)(nrow0 + srow) * 512 + scol;

    f32x4 acc[4][4];
#pragma unroll
    for (int i = 0; i < 4; ++i)
#pragma unroll
        for (int j = 0; j < 4; ++j)
            acc[i][j] = (f32x4){0.f, 0.f, 0.f, 0.f};

    for (int k0 = 0; k0 < 512; k0 += 32) {
#pragma unroll
        for (int c = 0; c < 4; ++c) {
            const int chunk = wave * 4 + c;        // 0..15
            gload_lds16(xg + (size_t)(chunk * 8) * 512 + k0, As + chunk * 256);
            gload_lds16(wg + (size_t)(chunk * 8) * 512 + k0, Bs + chunk * 256);
        }
        __syncthreads();                           // drains vmcnt before use

        bf16x8 af[4], bfr[4];
#pragma unroll
        for (int i = 0; i < 4; ++i)
            af[i] = cvt8(As + (wm * 64 + i * 16 + l15) * 32 + quad * 8);
#pragma unroll
        for (int j = 0; j < 4; ++j)
            bfr[j] = cvt8(Bs + (wn * 64 + j * 16 + l15) * 32 + quad * 8);

#pragma unroll
        for (int i = 0; i < 4; ++i)
#pragma unroll
            for (int j = 0; j < 4; ++j)
                acc[i][j] = MFMA16(af[i], bfr[j], acc[i][j]);

        __syncthreads();                           // before next stage overwrite
    }

    const float scale = (wsel == 0 || wsel == 2) ? 0.125f : 1.0f;
#pragma unroll
    for (int j = 0; j < 4; ++j) {
        const int ncol = nrow0 + wn * 64 + j * 16 + l15;   // 0..511 in weight
        float bias = 0.f;
        if (wsel == 1) bias = k1b[ncol];
        if (wsel == 3) bias = k2b[ncol];
        const int h = ncol >> 6, hd = ncol & 63;
#pragma unroll
        for (int i = 0; i < 4; ++i) {
#pragma unroll
            for (int r = 0; r < 4; ++r) {
                const int m = mb * 128 + wm * 64 + i * 16 + quad * 4 + r;
                const int bidx = m >> 11, s = m & 2047;
                const float v = acc[i][j][r] * scale + bias;
                if (wsel == 4) {
                    // permuted V^T store
                    const int s5 = s & 31;
                    const int p = ((s5 & 15) >> 2) * 8 + (s5 & 3) + ((s5 >> 4) << 2);
                    const int sp = (s & ~31) | p;
                    vto[((size_t)(bidx * 8 + h) * 64 + hd) * 2048 + sp] = (bf16)v;
                } else {
                    bf16* dst = (wsel == 0) ? q1o : (wsel == 1) ? k1o :
                                (wsel == 2) ? q2o : k2o;
                    dst[((size_t)(bidx * 8 + h) * 2048 + s) * 64 + hd] = (bf16)v;
                }
            }
        }
    }
}

// ---------------------------------------------------------------------------
// Kernel 2: dual-stream flash attention, transposed formulation, LDS-shared
// K/V. Block = 8 waves / 64 queries: wave w -> q-tile (w&3), key-half (w>>2).
// [unchanged from round 7]
// ---------------------------------------------------------------------------
__global__ __launch_bounds__(512, 4) void attn_kernel(
    const bf16* __restrict__ q1, const bf16* __restrict__ k1,
    const bf16* __restrict__ q2, const bf16* __restrict__ k2,
    const bf16* __restrict__ vt,
    const float* __restrict__ lq1, const float* __restrict__ lk1,
    const float* __restrict__ lq2, const float* __restrict__ lk2,
    bf16* __restrict__ o)
{
    __shared__ __align__(16) bf16 smem[12288];   // 24 KB: K1 | K2 | V
    __shared__ float lbuf[8][2][16];

    const int tid = threadIdx.x;
    const int wave = tid >> 6;
    const int lane = tid & 63;
    const int l15 = lane & 15, quad = lane >> 4;
    const int qtile = wave & 3;
    const int kg = wave >> 2;

    const int bh = blockIdx.x >> 5;
    const int qt = blockIdx.x & 31;
    const int b = bh >> 3, h = bh & 7;

    const bf16* k1t = k1 + (size_t)bh * 2048 * 64;
    const bf16* k2t = k2 + (size_t)bh * 2048 * 64;
    const bf16* vtt = vt + (size_t)bh * 64 * 2048;

    const int qrow = qt * 64 + qtile * 16 + l15;
    const bf16* q1p = q1 + ((size_t)bh * 2048 + qrow) * 64 + quad * 8;
    const bf16* q2p = q2 + ((size_t)bh * 2048 + qrow) * 64 + quad * 8;
    const bf16x8 q1f0 = *(const bf16x8*)(q1p);
    const bf16x8 q1f1 = *(const bf16x8*)(q1p + 32);
    const bf16x8 q2f0 = *(const bf16x8*)(q2p);
    const bf16x8 q2f1 = *(const bf16x8*)(q2p + 32);

    const int sw = wave & 3;
    const int skey0 = (wave < 4) ? 0 : 1024;
    bf16* k1dst = smem + wave * 512;
    bf16* k2dst = smem + 4096 + wave * 512;
    bf16* vdst  = smem + 8192 + wave * 512;
    const size_t ksrc0 = (size_t)skey0 * 64 + sw * 512 + lane * 8;
    const size_t vsrc0 = (size_t)(sw * 16 + (lane >> 2)) * 2048 + skey0 + (lane & 3) * 8;

    const bf16* k1r = smem + kg * 2048;
    const bf16* k2r = smem + 4096 + kg * 2048;
    const bf16* vr  = smem + 8192 + kg * 2048;

    f32x4 O1[4], O2[4];
    float l1 = 0.f, l2 = 0.f;
#pragma unroll
    for (int t = 0; t < 4; ++t) {
        O1[t] = (f32x4){0.f, 0.f, 0.f, 0.f};
        O2[t] = (f32x4){0.f, 0.f, 0.f, 0.f};
    }

    for (int it = 0; it < 32; ++it) {
        const size_t koff = ksrc0 + (size_t)it * 32 * 64;
        gload_lds16(k1t + koff, k1dst);
        gload_lds16(k2t + koff, k2dst);
        gload_lds16(vtt + vsrc0 + it * 32, vdst);
        __syncthreads();

        const bf16x8 k1t0a = *(const bf16x8*)(k1r + l15 * 64 + quad * 8);
        const bf16x8 k1t0b = *(const bf16x8*)(k1r + l15 * 64 + 32 + quad * 8);
        const bf16x8 k1t1a = *(const bf16x8*)(k1r + (16 + l15) * 64 + quad * 8);
        const bf16x8 k1t1b = *(const bf16x8*)(k1r + (16 + l15) * 64 + 32 + quad * 8);
        const bf16x8 k2t0a = *(const bf16x8*)(k2r + l15 * 64 + quad * 8);
        const bf16x8 k2t0b = *(const bf16x8*)(k2r + l15 * 64 + 32 + quad * 8);
        const bf16x8 k2t1a = *(const bf16x8*)(k2r + (16 + l15) * 64 + quad * 8);
        const bf16x8 k2t1b = *(const bf16x8*)(k2r + (16 + l15) * 64 + 32 + quad * 8);
        const bf16x8 v0 = *(const bf16x8*)(vr + l15 * 32 + quad * 8);
        const bf16x8 v1 = *(const bf16x8*)(vr + (16 + l15) * 32 + quad * 8);
        const bf16x8 v2 = *(const bf16x8*)(vr + (32 + l15) * 32 + quad * 8);
        const bf16x8 v3 = *(const bf16x8*)(vr + (48 + l15) * 32 + quad * 8);

        f32x4 z = (f32x4){0.f, 0.f, 0.f, 0.f};
        f32x4 s1t0 = MFMA16(k1t0a, q1f0, z);  s1t0 = MFMA16(k1t0b, q1f1, s1t0);
        f32x4 s1t1 = MFMA16(k1t1a, q1f0, z);  s1t1 = MFMA16(k1t1b, q1f1, s1t1);
        f32x4 s2t0 = MFMA16(k2t0a, q2f0, z);  s2t0 = MFMA16(k2t0b, q2f1, s2t0);
        f32x4 s2t1 = MFMA16(k2t1a, q2f0, z);  s2t1 = MFMA16(k2t1b, q2f1, s2t1);

        bf16x8 b1, b2;
#pragma unroll
        for (int r = 0; r < 4; ++r) {
            float e;
            e = __expf(s1t0[r]); l1 += e; b1[r]     = (bf16)e;
            e = __expf(s1t1[r]); l1 += e; b1[4 + r] = (bf16)e;
            e = __expf(s2t0[r]); l2 += e; b2[r]     = (bf16)e;
            e = __expf(s2t1[r]); l2 += e; b2[4 + r] = (bf16)e;
        }

        O1[0] = MFMA16(v0, b1, O1[0]);
        O1[1] = MFMA16(v1, b1, O1[1]);
        O1[2] = MFMA16(v2, b1, O1[2]);
        O1[3] = MFMA16(v3, b1, O1[3]);
        O2[0] = MFMA16(v0, b2, O2[0]);
        O2[1] = MFMA16(v1, b2, O2[1]);
        O2[2] = MFMA16(v2, b2, O2[2]);
        O2[3] = MFMA16(v3, b2, O2[3]);

        __syncthreads();
    }

    l1 += __shfl_xor(l1, 16, 64);  l1 += __shfl_xor(l1, 32, 64);
    l2 += __shfl_xor(l2, 16, 64);  l2 += __shfl_xor(l2, 32, 64);
    if (lane < 16) {
        lbuf[wave][0][lane] = l1;
        lbuf[wave][1][lane] = l2;
    }
    __syncthreads();

    f32x4* rb = (f32x4*)smem;
    if (wave == 4 || wave == 5) {
        f32x4* dst = rb + (wave - 4) * 512;
#pragma unroll
        for (int t = 0; t < 4; ++t) {
            dst[t * 64 + lane]       = O1[t];
            dst[(4 + t) * 64 + lane] = O2[t];
        }
    }
    __syncthreads();
    if (wave == 0 || wave == 1) {
        const f32x4* src = rb + wave * 512;
#pragma unroll
        for (int t = 0; t < 4; ++t) {
            O1[t] += src[t * 64 + lane];
            O2[t] += src[(4 + t) * 64 + lane];
        }
    }
    __syncthreads();
    if (wave == 6 || wave == 7) {
        f32x4* dst = rb + (wave - 6) * 512;
#pragma unroll
        for (int t = 0; t < 4; ++t) {
            dst[t * 64 + lane]       = O1[t];
            dst[(4 + t) * 64 + lane] = O2[t];
        }
    }
    __syncthreads();
    if (wave == 2 || wave == 3) {
        const f32x4* src = rb + (wave - 2) * 512;
#pragma unroll
        for (int t = 0; t < 4; ++t) {
            O1[t] += src[t * 64 + lane];
            O2[t] += src[(4 + t) * 64 + lane];
        }
    }

    if (wave < 4) {
        const float L1 = l1 + lbuf[wave + 4][0][l15];
        const float L2 = l2 + lbuf[wave + 4][1][l15];
        const float lam = __expf(lq1[h] * lk1[h]) - __expf(lq2[h] * lk2[h]) + LAMBDA_INIT;
        const float inv1 = 1.f / L1;
        const float inv2 = lam / L2;
        const size_t row = (size_t)(b * 2048 + qt * 64 + wave * 16 + l15) * 512 + h * 64;
#pragma unroll
        for (int t = 0; t < 4; ++t) {
#pragma unroll
            for (int r = 0; r < 4; ++r) {
                const float val = O1[t][r] * inv1 - O2[t][r] * inv2;
                o[row + t * 16 + quad * 4 + r] = (bf16)val;
            }
        }
    }
}

// ---------------------------------------------------------------------------
// Kernel 3: GroupNorm stats over (128 channels x 2048 s) per (b,g). [unchanged]
// ---------------------------------------------------------------------------
__global__ __launch_bounds__(256) void gn_stats_kernel(
    const bf16* __restrict__ o, float* __restrict__ stats)
{
    const int bg = blockIdx.x >> 4;
    const int chunk = blockIdx.x & 15;
    const int b = bg >> 2, g = bg & 3;

    float sum = 0.f, sumsq = 0.f;
    for (int i = threadIdx.x; i < 128 * 128; i += 256) {
        const int sr = i >> 7, c = i & 127;
        const float v = (float)o[((size_t)(b * 2048 + chunk * 128 + sr) * 512) + g * 128 + c];
        sum += v; sumsq += v * v;
    }
#pragma unroll
    for (int off = 1; off < 64; off <<= 1) {
        sum += __shfl_xor(sum, off, 64);
        sumsq += __shfl_xor(sumsq, off, 64);
    }
    __shared__ float red[2][4];
    const int wave = threadIdx.x >> 6, lane = threadIdx.x & 63;
    if (lane == 0) { red[0][wave] = sum; red[1][wave] = sumsq; }
    __syncthreads();
    if (threadIdx.x == 0) {
        float s0 = 0.f, s1 = 0.f;
        for (int w = 0; w < 4; ++w) { s0 += red[0][w]; s1 += red[1][w]; }
        atomicAdd(&stats[bg * 2], s0);
        atomicAdd(&stats[bg * 2 + 1], s1);
    }
}

// ---------------------------------------------------------------------------
// Kernel 4: apply GroupNorm affine -> xn (bf16). [unchanged]
// ---------------------------------------------------------------------------
__global__ __launch_bounds__(256) void gn_apply_kernel(
    const bf16* __restrict__ o, const float* __restrict__ stats,
    const float* __restrict__ gnw, const float* __restrict__ gnb,
    bf16* __restrict__ xn)
{
    const int idx = blockIdx.x * 256 + threadIdx.x;
    const int base = idx * 8;
    const int c = base & 511;
    const int b = base >> 20;
    const int g = c >> 7;
    const int bg = b * 4 + g;

    const float N = 128.f * 2048.f;
    const float mu = stats[bg * 2] / N;
    const float var = stats[bg * 2 + 1] / N - mu * mu;
    const float rstd = rsqrtf(var + EPS);

    const bf16x8 vals = *(const bf16x8*)(o + base);
    bf16x8 out;
#pragma unroll
    for (int j = 0; j < 8; ++j) {
        const float w = gnw[c + j];
        const float bb = gnb[c + j];
        out[j] = (bf16)(((float)vals[j] - mu) * rstd * w + bb);
    }
    *(bf16x8*)(xn + base) = out;
}

// ---------------------------------------------------------------------------
// Kernel 5: output GEMM y = xn @ out_w^T + out_b, y f32. [unchanged]
// ---------------------------------------------------------------------------
__global__ __launch_bounds__(256) void out_gemm_kernel(
    const bf16* __restrict__ xn, const float* __restrict__ ow,
    const float* __restrict__ ob, float* __restrict__ y)
{
    const int lane = threadIdx.x & 63;
    const int wave = threadIdx.x >> 6;
    const int l15 = lane & 15, quad = lane >> 4;

    const int tile = blockIdx.x * 4 + wave;
    const int mt = tile >> 4;
    const int nt = tile & 15;

    const bf16* ap[4];
#pragma unroll
    for (int i = 0; i < 4; ++i)
        ap[i] = xn + (size_t)(mt * 64 + i * 16 + l15) * 512 + quad * 8;
    const float* bp[2];
#pragma unroll
    for (int j = 0; j < 2; ++j)
        bp[j] = ow + (size_t)(nt * 32 + j * 16 + l15) * 512 + quad * 8;

    f32x4 acc[4][2];
#pragma unroll
    for (int i = 0; i < 4; ++i)
#pragma unroll
        for (int j = 0; j < 2; ++j)
            acc[i][j] = (f32x4){0.f, 0.f, 0.f, 0.f};

    for (int kk = 0; kk < 16; ++kk) {
        bf16x8 af[4], bfr[2];
#pragma unroll
        for (int i = 0; i < 4; ++i) af[i] = *(const bf16x8*)(ap[i] + kk * 32);
#pragma unroll
        for (int j = 0; j < 2; ++j) bfr[j] = cvt8(bp[j] + kk * 32);
#pragma unroll
        for (int i = 0; i < 4; ++i)
#pragma unroll
            for (int j = 0; j < 2; ++j)
                acc[i][j] = MFMA16(af[i], bfr[j], acc[i][j]);
    }

#pragma unroll
    for (int j = 0; j < 2; ++j) {
        const int ncol = nt * 32 + j * 16 + l15;
        const float bias = ob[ncol];
#pragma unroll
        for (int i = 0; i < 4; ++i) {
#pragma unroll
            for (int r = 0; r < 4; ++r) {
                const int m = mt * 64 + i * 16 + quad * 4 + r;
                y[(size_t)m * 512 + ncol] = acc[i][j][r] + bias;
            }
        }
    }
}

// ---------------------------------------------------------------------------
extern "C" void kernel_launch(void* const* d_in, const int* in_sizes, int n_in,
                              void* d_out, int out_size, void* d_ws, size_t ws_size,
                              hipStream_t stream)
{
    const float* x   = (const float*)d_in[0];
    const float* K1w = (const float*)d_in[1];
    const float* K1b = (const float*)d_in[2];
    const float* Q1w = (const float*)d_in[3];
    const float* K2w = (const float*)d_in[4];
    const float* K2b = (const float*)d_in[5];
    const float* Q2w = (const float*)d_in[6];
    const float* Vw  = (const float*)d_in[7];
    const float* lq1 = (const float*)d_in[8];
    const float* lk1 = (const float*)d_in[9];
    const float* lq2 = (const float*)d_in[10];
    const float* lk2 = (const float*)d_in[11];
    const float* gnw = (const float*)d_in[12];
    const float* gnb = (const float*)d_in[13];
    const float* Ow  = (const float*)d_in[14];
    const float* Ob  = (const float*)d_in[15];

    const size_t SZ = (size_t)2 * 8 * 2048 * 64;   // 2M elements per tensor
    bf16* q1 = (bf16*)d_ws;
    bf16* k1 = q1 + SZ;
    bf16* q2 = k1 + SZ;
    bf16* k2 = q2 + SZ;
    bf16* vt = k2 + SZ;
    float* stats = (float*)(vt + SZ);

    bf16* o  = (bf16*)d_out;   // scratch in d_out; fully overwritten by out_gemm
    bf16* xn = q1;             // q1 slot dead after attn_kernel

    hipMemsetAsync(stats, 0, 16 * sizeof(float), stream);

    proj_kernel<<<640, 256, 0, stream>>>(x, Q1w, K1w, Q2w, K2w, Vw, K1b, K2b,
                                         q1, k1, q2, k2, vt);
    attn_kernel<<<512, 512, 0, stream>>>(q1, k1, q2, k2, vt,
                                         lq1, lk1, lq2, lk2, o);
    gn_stats_kernel<<<128, 256, 0, stream>>>(o, stats);
    gn_apply_kernel<<<1024, 256, 0, stream>>>(o, stats, gnw, gnb, xn);
    out_gemm_kernel<<<256, 256, 0, stream>>>(xn, Ow, Ob, (float*)d_out);
}

// Round 9
// 202.358 us; speedup vs baseline: 1.9790x; 1.0738x over previous
//
#include <hip/hip_runtime.h>
#include <hip/hip_bf16.h>

typedef __bf16 bf16;
typedef __attribute__((ext_vector_type(8))) __bf16 bf16x8;
typedef __attribute__((ext_vector_type(4))) float f32x4;

#define MFMA16(a, b, c) __builtin_amdgcn_mfma_f32_16x16x32_bf16((a), (b), (c), 0, 0, 0)

// B=2, S=2048, D=512, H=8, hd=64, G=4. All I/O float32; bf16 MFMA compute.
static constexpr float EPS = 1e-5f;
static constexpr float LAMBDA_INIT = 0.2f;

// Load 8 consecutive f32 (32B, 16B-aligned) and convert to bf16x8.
__device__ __forceinline__ bf16x8 cvt8(const float* p) {
    const f32x4 a = *(const f32x4*)p;
    const f32x4 b = *(const f32x4*)(p + 4);
    bf16x8 r;
    r[0] = (bf16)a[0]; r[1] = (bf16)a[1]; r[2] = (bf16)a[2]; r[3] = (bf16)a[3];
    r[4] = (bf16)b[0]; r[5] = (bf16)b[1]; r[6] = (bf16)b[2]; r[7] = (bf16)b[3];
    return r;
}

// Async 16B global -> LDS (lane i lands at lds_base + i*16; base wave-uniform).
__device__ __forceinline__ void gload_lds16(const void* g, void* l) {
    __builtin_amdgcn_global_load_lds(
        (const __attribute__((address_space(1))) unsigned int*)g,
        (__attribute__((address_space(3))) unsigned int*)l,
        16, 0, 0);
}

// ---------------------------------------------------------------------------
// Kernel 1: fused QKV projection GEMM (f32 in -> bf16 out), m97-style.
// [unchanged from round 8]
// ---------------------------------------------------------------------------
__global__ __launch_bounds__(256) void proj_kernel(
    const float* __restrict__ x,
    const float* __restrict__ q1w, const float* __restrict__ k1w,
    const float* __restrict__ q2w, const float* __restrict__ k2w,
    const float* __restrict__ vw,
    const float* __restrict__ k1b, const float* __restrict__ k2b,
    bf16* __restrict__ q1o, bf16* __restrict__ k1o,
    bf16* __restrict__ q2o, bf16* __restrict__ k2o,
    bf16* __restrict__ vto)
{
    __shared__ __align__(16) float As[128 * 32];   // 16 KB
    __shared__ __align__(16) float Bs[128 * 32];   // 16 KB

    const int tid = threadIdx.x;
    const int wave = tid >> 6, lane = tid & 63;
    const int l15 = lane & 15, quad = lane >> 4;
    const int wm = wave >> 1, wn = wave & 1;

    const int mb = blockIdx.x / 20;
    const int nb = blockIdx.x % 20;
    const int wsel = nb >> 2;
    const int nrow0 = (nb & 3) * 128;

    const float* W = (wsel == 0) ? q1w : (wsel == 1) ? k1w :
                     (wsel == 2) ? q2w : (wsel == 3) ? k2w : vw;

    const int srow = lane >> 3;
    const int scol = (lane & 7) * 4;
    const float* xg = x + (size_t)(mb * 128 + srow) * 512 + scol;
    const float* wg = W + (size_t)(nrow0 + srow) * 512 + scol;

    f32x4 acc[4][4];
#pragma unroll
    for (int i = 0; i < 4; ++i)
#pragma unroll
        for (int j = 0; j < 4; ++j)
            acc[i][j] = (f32x4){0.f, 0.f, 0.f, 0.f};

    for (int k0 = 0; k0 < 512; k0 += 32) {
#pragma unroll
        for (int c = 0; c < 4; ++c) {
            const int chunk = wave * 4 + c;
            gload_lds16(xg + (size_t)(chunk * 8) * 512 + k0, As + chunk * 256);
            gload_lds16(wg + (size_t)(chunk * 8) * 512 + k0, Bs + chunk * 256);
        }
        __syncthreads();

        bf16x8 af[4], bfr[4];
#pragma unroll
        for (int i = 0; i < 4; ++i)
            af[i] = cvt8(As + (wm * 64 + i * 16 + l15) * 32 + quad * 8);
#pragma unroll
        for (int j = 0; j < 4; ++j)
            bfr[j] = cvt8(Bs + (wn * 64 + j * 16 + l15) * 32 + quad * 8);

#pragma unroll
        for (int i = 0; i < 4; ++i)
#pragma unroll
            for (int j = 0; j < 4; ++j)
                acc[i][j] = MFMA16(af[i], bfr[j], acc[i][j]);

        __syncthreads();
    }

    const float scale = (wsel == 0 || wsel == 2) ? 0.125f : 1.0f;
#pragma unroll
    for (int j = 0; j < 4; ++j) {
        const int ncol = nrow0 + wn * 64 + j * 16 + l15;
        float bias = 0.f;
        if (wsel == 1) bias = k1b[ncol];
        if (wsel == 3) bias = k2b[ncol];
        const int h = ncol >> 6, hd = ncol & 63;
#pragma unroll
        for (int i = 0; i < 4; ++i) {
#pragma unroll
            for (int r = 0; r < 4; ++r) {
                const int m = mb * 128 + wm * 64 + i * 16 + quad * 4 + r;
                const int bidx = m >> 11, s = m & 2047;
                const float v = acc[i][j][r] * scale + bias;
                if (wsel == 4) {
                    const int s5 = s & 31;
                    const int p = ((s5 & 15) >> 2) * 8 + (s5 & 3) + ((s5 >> 4) << 2);
                    const int sp = (s & ~31) | p;
                    vto[((size_t)(bidx * 8 + h) * 64 + hd) * 2048 + sp] = (bf16)v;
                } else {
                    bf16* dst = (wsel == 0) ? q1o : (wsel == 1) ? k1o :
                                (wsel == 2) ? q2o : k2o;
                    dst[((size_t)(bidx * 8 + h) * 2048 + s) * 64 + hd] = (bf16)v;
                }
            }
        }
    }
}

// ---------------------------------------------------------------------------
// Kernel 2: dual-stream flash attention + fused GroupNorm partial stats.
// K tiles stored bank-swizzled in LDS: element (key,d) at
//   key*64 + (d ^ ((key&7)*8))   -> conflict-free ds_read_b128 K-frags.
// Epilogue: block-wide sum/sumsq of o-values -> 2 atomicAdds into stats.
// ---------------------------------------------------------------------------
__global__ __launch_bounds__(512, 4) void attn_kernel(
    const bf16* __restrict__ q1, const bf16* __restrict__ k1,
    const bf16* __restrict__ q2, const bf16* __restrict__ k2,
    const bf16* __restrict__ vt,
    const float* __restrict__ lq1, const float* __restrict__ lk1,
    const float* __restrict__ lq2, const float* __restrict__ lk2,
    bf16* __restrict__ o, float* __restrict__ stats)
{
    __shared__ __align__(16) bf16 smem[12288];   // 24 KB: K1 | K2 | V
    __shared__ float lbuf[8][2][16];
    __shared__ float sred[8][2];

    const int tid = threadIdx.x;
    const int wave = tid >> 6;
    const int lane = tid & 63;
    const int l15 = lane & 15, quad = lane >> 4;
    const int qtile = wave & 3;
    const int kg = wave >> 2;

    const int bh = blockIdx.x >> 5;
    const int qt = blockIdx.x & 31;
    const int b = bh >> 3, h = bh & 7;

    const bf16* k1t = k1 + (size_t)bh * 2048 * 64;
    const bf16* k2t = k2 + (size_t)bh * 2048 * 64;
    const bf16* vtt = vt + (size_t)bh * 64 * 2048;

    const int qrow = qt * 64 + qtile * 16 + l15;
    const bf16* q1p = q1 + ((size_t)bh * 2048 + qrow) * 64 + quad * 8;
    const bf16* q2p = q2 + ((size_t)bh * 2048 + qrow) * 64 + quad * 8;
    const bf16x8 q1f0 = *(const bf16x8*)(q1p);
    const bf16x8 q1f1 = *(const bf16x8*)(q1p + 32);
    const bf16x8 q2f0 = *(const bf16x8*)(q2p);
    const bf16x8 q2f1 = *(const bf16x8*)(q2p + 32);

    const int sw = wave & 3;
    const int skey0 = (wave < 4) ? 0 : 1024;
    bf16* k1dst = smem + wave * 512;
    bf16* k2dst = smem + 4096 + wave * 512;
    bf16* vdst  = smem + 8192 + wave * 512;
    // K staging source: swizzled so LDS holds (key,d) at key*64 + (d ^ (key&7)*8)
    const size_t ksrc0 = (size_t)(skey0 + sw * 8 + (lane >> 3)) * 64
                       + 8 * ((lane & 7) ^ (lane >> 3));
    const size_t vsrc0 = (size_t)(sw * 16 + (lane >> 2)) * 2048 + skey0 + (lane & 3) * 8;

    const bf16* k1r = smem + kg * 2048;
    const bf16* k2r = smem + 4096 + kg * 2048;
    const bf16* vr  = smem + 8192 + kg * 2048;

    // Swizzled K-frag read offsets (8 consecutive bf16 each, 16B aligned).
    const int koffa = 8 * (quad ^ (l15 & 7));          // d-block quad
    const int koffb = 8 * ((quad + 4) ^ (l15 & 7));    // d-block quad+4 (d>=32)

    f32x4 O1[4], O2[4];
    float l1 = 0.f, l2 = 0.f;
#pragma unroll
    for (int t = 0; t < 4; ++t) {
        O1[t] = (f32x4){0.f, 0.f, 0.f, 0.f};
        O2[t] = (f32x4){0.f, 0.f, 0.f, 0.f};
    }

    for (int it = 0; it < 32; ++it) {
        const size_t koff = ksrc0 + (size_t)it * 32 * 64;
        gload_lds16(k1t + koff, k1dst);
        gload_lds16(k2t + koff, k2dst);
        gload_lds16(vtt + vsrc0 + it * 32, vdst);
        __syncthreads();

        const bf16x8 k1t0a = *(const bf16x8*)(k1r + l15 * 64 + koffa);
        const bf16x8 k1t0b = *(const bf16x8*)(k1r + l15 * 64 + koffb);
        const bf16x8 k1t1a = *(const bf16x8*)(k1r + (16 + l15) * 64 + koffa);
        const bf16x8 k1t1b = *(const bf16x8*)(k1r + (16 + l15) * 64 + koffb);
        const bf16x8 k2t0a = *(const bf16x8*)(k2r + l15 * 64 + koffa);
        const bf16x8 k2t0b = *(const bf16x8*)(k2r + l15 * 64 + koffb);
        const bf16x8 k2t1a = *(const bf16x8*)(k2r + (16 + l15) * 64 + koffa);
        const bf16x8 k2t1b = *(const bf16x8*)(k2r + (16 + l15) * 64 + koffb);
        const bf16x8 v0 = *(const bf16x8*)(vr + l15 * 32 + quad * 8);
        const bf16x8 v1 = *(const bf16x8*)(vr + (16 + l15) * 32 + quad * 8);
        const bf16x8 v2 = *(const bf16x8*)(vr + (32 + l15) * 32 + quad * 8);
        const bf16x8 v3 = *(const bf16x8*)(vr + (48 + l15) * 32 + quad * 8);

        f32x4 z = (f32x4){0.f, 0.f, 0.f, 0.f};
        f32x4 s1t0 = MFMA16(k1t0a, q1f0, z);  s1t0 = MFMA16(k1t0b, q1f1, s1t0);
        f32x4 s1t1 = MFMA16(k1t1a, q1f0, z);  s1t1 = MFMA16(k1t1b, q1f1, s1t1);
        f32x4 s2t0 = MFMA16(k2t0a, q2f0, z);  s2t0 = MFMA16(k2t0b, q2f1, s2t0);
        f32x4 s2t1 = MFMA16(k2t1a, q2f0, z);  s2t1 = MFMA16(k2t1b, q2f1, s2t1);

        bf16x8 b1, b2;
#pragma unroll
        for (int r = 0; r < 4; ++r) {
            float e;
            e = __expf(s1t0[r]); l1 += e; b1[r]     = (bf16)e;
            e = __expf(s1t1[r]); l1 += e; b1[4 + r] = (bf16)e;
            e = __expf(s2t0[r]); l2 += e; b2[r]     = (bf16)e;
            e = __expf(s2t1[r]); l2 += e; b2[4 + r] = (bf16)e;
        }

        O1[0] = MFMA16(v0, b1, O1[0]);
        O1[1] = MFMA16(v1, b1, O1[1]);
        O1[2] = MFMA16(v2, b1, O1[2]);
        O1[3] = MFMA16(v3, b1, O1[3]);
        O2[0] = MFMA16(v0, b2, O2[0]);
        O2[1] = MFMA16(v1, b2, O2[1]);
        O2[2] = MFMA16(v2, b2, O2[2]);
        O2[3] = MFMA16(v3, b2, O2[3]);

        __syncthreads();
    }

    l1 += __shfl_xor(l1, 16, 64);  l1 += __shfl_xor(l1, 32, 64);
    l2 += __shfl_xor(l2, 16, 64);  l2 += __shfl_xor(l2, 32, 64);
    if (lane < 16) {
        lbuf[wave][0][lane] = l1;
        lbuf[wave][1][lane] = l2;
    }
    __syncthreads();

    f32x4* rb = (f32x4*)smem;
    if (wave == 4 || wave == 5) {
        f32x4* dst = rb + (wave - 4) * 512;
#pragma unroll
        for (int t = 0; t < 4; ++t) {
            dst[t * 64 + lane]       = O1[t];
            dst[(4 + t) * 64 + lane] = O2[t];
        }
    }
    __syncthreads();
    if (wave == 0 || wave == 1) {
        const f32x4* src = rb + wave * 512;
#pragma unroll
        for (int t = 0; t < 4; ++t) {
            O1[t] += src[t * 64 + lane];
            O2[t] += src[(4 + t) * 64 + lane];
        }
    }
    __syncthreads();
    if (wave == 6 || wave == 7) {
        f32x4* dst = rb + (wave - 6) * 512;
#pragma unroll
        for (int t = 0; t < 4; ++t) {
            dst[t * 64 + lane]       = O1[t];
            dst[(4 + t) * 64 + lane] = O2[t];
        }
    }
    __syncthreads();
    if (wave == 2 || wave == 3) {
        const f32x4* src = rb + (wave - 2) * 512;
#pragma unroll
        for (int t = 0; t < 4; ++t) {
            O1[t] += src[t * 64 + lane];
            O2[t] += src[(4 + t) * 64 + lane];
        }
    }

    float ssum = 0.f, ssq = 0.f;
    if (wave < 4) {
        const float L1 = l1 + lbuf[wave + 4][0][l15];
        const float L2 = l2 + lbuf[wave + 4][1][l15];
        const float lam = __expf(lq1[h] * lk1[h]) - __expf(lq2[h] * lk2[h]) + LAMBDA_INIT;
        const float inv1 = 1.f / L1;
        const float inv2 = lam / L2;
        const size_t row = (size_t)(b * 2048 + qt * 64 + wave * 16 + l15) * 512 + h * 64;
#pragma unroll
        for (int t = 0; t < 4; ++t) {
#pragma unroll
            for (int r = 0; r < 4; ++r) {
                const float val = O1[t][r] * inv1 - O2[t][r] * inv2;
                ssum += val;
                ssq += val * val;
                o[row + t * 16 + quad * 4 + r] = (bf16)val;
            }
        }
    }
    // Block-wide GroupNorm partial stats (this block's channels all lie in
    // group g = h>>1 of batch b).
#pragma unroll
    for (int off = 1; off < 64; off <<= 1) {
        ssum += __shfl_xor(ssum, off, 64);
        ssq += __shfl_xor(ssq, off, 64);
    }
    if (lane == 0) { sred[wave][0] = ssum; sred[wave][1] = ssq; }
    __syncthreads();
    if (tid == 0) {
        float s0 = 0.f, s1 = 0.f;
        for (int w = 0; w < 8; ++w) { s0 += sred[w][0]; s1 += sred[w][1]; }
        const int bg = b * 4 + (h >> 1);
        atomicAdd(&stats[bg * 2], s0);
        atomicAdd(&stats[bg * 2 + 1], s1);
    }
}

// ---------------------------------------------------------------------------
// Kernel 3: output GEMM with fused GroupNorm apply:
// y = GN(o) @ out_w^T + out_b,  GN applied per A-fragment element
// (per kk the channel range lies in one group: g = kk>>2).
// ---------------------------------------------------------------------------
__global__ __launch_bounds__(256) void out_gemm_kernel(
    const bf16* __restrict__ o, const float* __restrict__ stats,
    const float* __restrict__ gnw, const float* __restrict__ gnb,
    const float* __restrict__ ow, const float* __restrict__ ob,
    float* __restrict__ y)
{
    const int lane = threadIdx.x & 63;
    const int wave = threadIdx.x >> 6;
    const int l15 = lane & 15, quad = lane >> 4;

    const int tile = blockIdx.x * 4 + wave;
    const int mt = tile >> 4;          // 64 m-tiles of 64 rows
    const int nt = tile & 15;          // 16 n-tiles of 32 cols
    const int b = mt >> 5;             // batch (rows don't cross 2048)

    // Per-group normalization constants for this batch.
    const float N = 128.f * 2048.f;
    float mu[4], rs[4];
#pragma unroll
    for (int g = 0; g < 4; ++g) {
        const float m = stats[(b * 4 + g) * 2] / N;
        const float var = stats[(b * 4 + g) * 2 + 1] / N - m * m;
        mu[g] = m;
        rs[g] = rsqrtf(var + EPS);
    }

    const bf16* ap[4];
#pragma unroll
    for (int i = 0; i < 4; ++i)
        ap[i] = o + (size_t)(mt * 64 + i * 16 + l15) * 512 + quad * 8;
    const float* bp[2];
#pragma unroll
    for (int j = 0; j < 2; ++j)
        bp[j] = ow + (size_t)(nt * 32 + j * 16 + l15) * 512 + quad * 8;

    f32x4 acc[4][2];
#pragma unroll
    for (int i = 0; i < 4; ++i)
#pragma unroll
        for (int j = 0; j < 2; ++j)
            acc[i][j] = (f32x4){0.f, 0.f, 0.f, 0.f};

    for (int kk = 0; kk < 16; ++kk) {
        const int g = kk >> 2;
        const int c0 = kk * 32 + quad * 8;
        const f32x4 w0 = *(const f32x4*)(gnw + c0);
        const f32x4 w1 = *(const f32x4*)(gnw + c0 + 4);
        const f32x4 g0 = *(const f32x4*)(gnb + c0);
        const f32x4 g1 = *(const f32x4*)(gnb + c0 + 4);
        float weff[8], beff[8];
#pragma unroll
        for (int j = 0; j < 4; ++j) {
            weff[j] = w0[j] * rs[g];  beff[j] = g0[j] - mu[g] * weff[j];
            weff[4 + j] = w1[j] * rs[g];  beff[4 + j] = g1[j] - mu[g] * weff[4 + j];
        }

        bf16x8 af[4], bfr[2];
#pragma unroll
        for (int i = 0; i < 4; ++i) {
            const bf16x8 ov = *(const bf16x8*)(ap[i] + kk * 32);
#pragma unroll
            for (int j = 0; j < 8; ++j)
                af[i][j] = (bf16)((float)ov[j] * weff[j] + beff[j]);
        }
#pragma unroll
        for (int j = 0; j < 2; ++j) bfr[j] = cvt8(bp[j] + kk * 32);
#pragma unroll
        for (int i = 0; i < 4; ++i)
#pragma unroll
            for (int j = 0; j < 2; ++j)
                acc[i][j] = MFMA16(af[i], bfr[j], acc[i][j]);
    }

#pragma unroll
    for (int j = 0; j < 2; ++j) {
        const int ncol = nt * 32 + j * 16 + l15;
        const float bias = ob[ncol];
#pragma unroll
        for (int i = 0; i < 4; ++i) {
#pragma unroll
            for (int r = 0; r < 4; ++r) {
                const int m = mt * 64 + i * 16 + quad * 4 + r;
                y[(size_t)m * 512 + ncol] = acc[i][j][r] + bias;
            }
        }
    }
}

// ---------------------------------------------------------------------------
extern "C" void kernel_launch(void* const* d_in, const int* in_sizes, int n_in,
                              void* d_out, int out_size, void* d_ws, size_t ws_size,
                              hipStream_t stream)
{
    const float* x   = (const float*)d_in[0];
    const float* K1w = (const float*)d_in[1];
    const float* K1b = (const float*)d_in[2];
    const float* Q1w = (const float*)d_in[3];
    const float* K2w = (const float*)d_in[4];
    const float* K2b = (const float*)d_in[5];
    const float* Q2w = (const float*)d_in[6];
    const float* Vw  = (const float*)d_in[7];
    const float* lq1 = (const float*)d_in[8];
    const float* lk1 = (const float*)d_in[9];
    const float* lq2 = (const float*)d_in[10];
    const float* lk2 = (const float*)d_in[11];
    const float* gnw = (const float*)d_in[12];
    const float* gnb = (const float*)d_in[13];
    const float* Ow  = (const float*)d_in[14];
    const float* Ob  = (const float*)d_in[15];

    const size_t SZ = (size_t)2 * 8 * 2048 * 64;   // 2M elements per tensor
    bf16* q1 = (bf16*)d_ws;
    bf16* k1 = q1 + SZ;
    bf16* q2 = k1 + SZ;
    bf16* k2 = q2 + SZ;
    bf16* vt = k2 + SZ;
    bf16* o  = vt + SZ;                 // attention output (ws; d_out is GEMM-only)
    float* stats = (float*)(o + SZ);

    hipMemsetAsync(stats, 0, 16 * sizeof(float), stream);

    proj_kernel<<<640, 256, 0, stream>>>(x, Q1w, K1w, Q2w, K2w, Vw, K1b, K2b,
                                         q1, k1, q2, k2, vt);
    attn_kernel<<<512, 512, 0, stream>>>(q1, k1, q2, k2, vt,
                                         lq1, lk1, lq2, lk2, o, stats);
    out_gemm_kernel<<<256, 256, 0, stream>>>(o, stats, gnw, gnb, Ow, Ob,
                                             (float*)d_out);
}

// Round 10
// 200.358 us; speedup vs baseline: 1.9987x; 1.0100x over previous
//
#include <hip/hip_runtime.h>
#include <hip/hip_bf16.h>

typedef __bf16 bf16;
typedef __attribute__((ext_vector_type(8))) __bf16 bf16x8;
typedef __attribute__((ext_vector_type(4))) float f32x4;

#define MFMA16(a, b, c) __builtin_amdgcn_mfma_f32_16x16x32_bf16((a), (b), (c), 0, 0, 0)

// B=2, S=2048, D=512, H=8, hd=64, G=4. All I/O float32; bf16 MFMA compute.
static constexpr float EPS = 1e-5f;
static constexpr float LAMBDA_INIT = 0.2f;

// Load 8 consecutive f32 (32B, 16B-aligned) and convert to bf16x8.
__device__ __forceinline__ bf16x8 cvt8(const float* p) {
    const f32x4 a = *(const f32x4*)p;
    const f32x4 b = *(const f32x4*)(p + 4);
    bf16x8 r;
    r[0] = (bf16)a[0]; r[1] = (bf16)a[1]; r[2] = (bf16)a[2]; r[3] = (bf16)a[3];
    r[4] = (bf16)b[0]; r[5] = (bf16)b[1]; r[6] = (bf16)b[2]; r[7] = (bf16)b[3];
    return r;
}

// Async 16B global -> LDS (lane i lands at lds_base + i*16; base wave-uniform).
__device__ __forceinline__ void gload_lds16(const void* g, void* l) {
    __builtin_amdgcn_global_load_lds(
        (const __attribute__((address_space(1))) unsigned int*)g,
        (__attribute__((address_space(3))) unsigned int*)l,
        16, 0, 0);
}

// ---------------------------------------------------------------------------
// Kernel 1: fused QKV projection GEMM (f32 in -> bf16 out), m97-style.
// [unchanged from round 9]
// ---------------------------------------------------------------------------
__global__ __launch_bounds__(256) void proj_kernel(
    const float* __restrict__ x,
    const float* __restrict__ q1w, const float* __restrict__ k1w,
    const float* __restrict__ q2w, const float* __restrict__ k2w,
    const float* __restrict__ vw,
    const float* __restrict__ k1b, const float* __restrict__ k2b,
    bf16* __restrict__ q1o, bf16* __restrict__ k1o,
    bf16* __restrict__ q2o, bf16* __restrict__ k2o,
    bf16* __restrict__ vto)
{
    __shared__ __align__(16) float As[128 * 32];   // 16 KB
    __shared__ __align__(16) float Bs[128 * 32];   // 16 KB

    const int tid = threadIdx.x;
    const int wave = tid >> 6, lane = tid & 63;
    const int l15 = lane & 15, quad = lane >> 4;
    const int wm = wave >> 1, wn = wave & 1;

    const int mb = blockIdx.x / 20;
    const int nb = blockIdx.x % 20;
    const int wsel = nb >> 2;
    const int nrow0 = (nb & 3) * 128;

    const float* W = (wsel == 0) ? q1w : (wsel == 1) ? k1w :
                     (wsel == 2) ? q2w : (wsel == 3) ? k2w : vw;

    const int srow = lane >> 3;
    const int scol = (lane & 7) * 4;
    const float* xg = x + (size_t)(mb * 128 + srow) * 512 + scol;
    const float* wg = W + (size_t)(nrow0 + srow) * 512 + scol;

    f32x4 acc[4][4];
#pragma unroll
    for (int i = 0; i < 4; ++i)
#pragma unroll
        for (int j = 0; j < 4; ++j)
            acc[i][j] = (f32x4){0.f, 0.f, 0.f, 0.f};

    for (int k0 = 0; k0 < 512; k0 += 32) {
#pragma unroll
        for (int c = 0; c < 4; ++c) {
            const int chunk = wave * 4 + c;
            gload_lds16(xg + (size_t)(chunk * 8) * 512 + k0, As + chunk * 256);
            gload_lds16(wg + (size_t)(chunk * 8) * 512 + k0, Bs + chunk * 256);
        }
        __syncthreads();

        bf16x8 af[4], bfr[4];
#pragma unroll
        for (int i = 0; i < 4; ++i)
            af[i] = cvt8(As + (wm * 64 + i * 16 + l15) * 32 + quad * 8);
#pragma unroll
        for (int j = 0; j < 4; ++j)
            bfr[j] = cvt8(Bs + (wn * 64 + j * 16 + l15) * 32 + quad * 8);

#pragma unroll
        for (int i = 0; i < 4; ++i)
#pragma unroll
            for (int j = 0; j < 4; ++j)
                acc[i][j] = MFMA16(af[i], bfr[j], acc[i][j]);

        __syncthreads();
    }

    const float scale = (wsel == 0 || wsel == 2) ? 0.125f : 1.0f;
#pragma unroll
    for (int j = 0; j < 4; ++j) {
        const int ncol = nrow0 + wn * 64 + j * 16 + l15;
        float bias = 0.f;
        if (wsel == 1) bias = k1b[ncol];
        if (wsel == 3) bias = k2b[ncol];
        const int h = ncol >> 6, hd = ncol & 63;
#pragma unroll
        for (int i = 0; i < 4; ++i) {
#pragma unroll
            for (int r = 0; r < 4; ++r) {
                const int m = mb * 128 + wm * 64 + i * 16 + quad * 4 + r;
                const int bidx = m >> 11, s = m & 2047;
                const float v = acc[i][j][r] * scale + bias;
                if (wsel == 4) {
                    const int s5 = s & 31;
                    const int p = ((s5 & 15) >> 2) * 8 + (s5 & 3) + ((s5 >> 4) << 2);
                    const int sp = (s & ~31) | p;
                    vto[((size_t)(bidx * 8 + h) * 64 + hd) * 2048 + sp] = (bf16)v;
                } else {
                    bf16* dst = (wsel == 0) ? q1o : (wsel == 1) ? k1o :
                                (wsel == 2) ? q2o : k2o;
                    dst[((size_t)(bidx * 8 + h) * 2048 + s) * 64 + hd] = (bf16)v;
                }
            }
        }
    }
}

// ---------------------------------------------------------------------------
// Kernel 2: dual-stream flash attention + fused GroupNorm partial stats.
// [unchanged from round 9]
// ---------------------------------------------------------------------------
__global__ __launch_bounds__(512, 4) void attn_kernel(
    const bf16* __restrict__ q1, const bf16* __restrict__ k1,
    const bf16* __restrict__ q2, const bf16* __restrict__ k2,
    const bf16* __restrict__ vt,
    const float* __restrict__ lq1, const float* __restrict__ lk1,
    const float* __restrict__ lq2, const float* __restrict__ lk2,
    bf16* __restrict__ o, float* __restrict__ stats)
{
    __shared__ __align__(16) bf16 smem[12288];   // 24 KB: K1 | K2 | V
    __shared__ float lbuf[8][2][16];
    __shared__ float sred[8][2];

    const int tid = threadIdx.x;
    const int wave = tid >> 6;
    const int lane = tid & 63;
    const int l15 = lane & 15, quad = lane >> 4;
    const int qtile = wave & 3;
    const int kg = wave >> 2;

    const int bh = blockIdx.x >> 5;
    const int qt = blockIdx.x & 31;
    const int b = bh >> 3, h = bh & 7;

    const bf16* k1t = k1 + (size_t)bh * 2048 * 64;
    const bf16* k2t = k2 + (size_t)bh * 2048 * 64;
    const bf16* vtt = vt + (size_t)bh * 64 * 2048;

    const int qrow = qt * 64 + qtile * 16 + l15;
    const bf16* q1p = q1 + ((size_t)bh * 2048 + qrow) * 64 + quad * 8;
    const bf16* q2p = q2 + ((size_t)bh * 2048 + qrow) * 64 + quad * 8;
    const bf16x8 q1f0 = *(const bf16x8*)(q1p);
    const bf16x8 q1f1 = *(const bf16x8*)(q1p + 32);
    const bf16x8 q2f0 = *(const bf16x8*)(q2p);
    const bf16x8 q2f1 = *(const bf16x8*)(q2p + 32);

    const int sw = wave & 3;
    const int skey0 = (wave < 4) ? 0 : 1024;
    bf16* k1dst = smem + wave * 512;
    bf16* k2dst = smem + 4096 + wave * 512;
    bf16* vdst  = smem + 8192 + wave * 512;
    const size_t ksrc0 = (size_t)(skey0 + sw * 8 + (lane >> 3)) * 64
                       + 8 * ((lane & 7) ^ (lane >> 3));
    const size_t vsrc0 = (size_t)(sw * 16 + (lane >> 2)) * 2048 + skey0 + (lane & 3) * 8;

    const bf16* k1r = smem + kg * 2048;
    const bf16* k2r = smem + 4096 + kg * 2048;
    const bf16* vr  = smem + 8192 + kg * 2048;

    const int koffa = 8 * (quad ^ (l15 & 7));
    const int koffb = 8 * ((quad + 4) ^ (l15 & 7));

    f32x4 O1[4], O2[4];
    float l1 = 0.f, l2 = 0.f;
#pragma unroll
    for (int t = 0; t < 4; ++t) {
        O1[t] = (f32x4){0.f, 0.f, 0.f, 0.f};
        O2[t] = (f32x4){0.f, 0.f, 0.f, 0.f};
    }

    for (int it = 0; it < 32; ++it) {
        const size_t koff = ksrc0 + (size_t)it * 32 * 64;
        gload_lds16(k1t + koff, k1dst);
        gload_lds16(k2t + koff, k2dst);
        gload_lds16(vtt + vsrc0 + it * 32, vdst);
        __syncthreads();

        const bf16x8 k1t0a = *(const bf16x8*)(k1r + l15 * 64 + koffa);
        const bf16x8 k1t0b = *(const bf16x8*)(k1r + l15 * 64 + koffb);
        const bf16x8 k1t1a = *(const bf16x8*)(k1r + (16 + l15) * 64 + koffa);
        const bf16x8 k1t1b = *(const bf16x8*)(k1r + (16 + l15) * 64 + koffb);
        const bf16x8 k2t0a = *(const bf16x8*)(k2r + l15 * 64 + koffa);
        const bf16x8 k2t0b = *(const bf16x8*)(k2r + l15 * 64 + koffb);
        const bf16x8 k2t1a = *(const bf16x8*)(k2r + (16 + l15) * 64 + koffa);
        const bf16x8 k2t1b = *(const bf16x8*)(k2r + (16 + l15) * 64 + koffb);
        const bf16x8 v0 = *(const bf16x8*)(vr + l15 * 32 + quad * 8);
        const bf16x8 v1 = *(const bf16x8*)(vr + (16 + l15) * 32 + quad * 8);
        const bf16x8 v2 = *(const bf16x8*)(vr + (32 + l15) * 32 + quad * 8);
        const bf16x8 v3 = *(const bf16x8*)(vr + (48 + l15) * 32 + quad * 8);

        f32x4 z = (f32x4){0.f, 0.f, 0.f, 0.f};
        f32x4 s1t0 = MFMA16(k1t0a, q1f0, z);  s1t0 = MFMA16(k1t0b, q1f1, s1t0);
        f32x4 s1t1 = MFMA16(k1t1a, q1f0, z);  s1t1 = MFMA16(k1t1b, q1f1, s1t1);
        f32x4 s2t0 = MFMA16(k2t0a, q2f0, z);  s2t0 = MFMA16(k2t0b, q2f1, s2t0);
        f32x4 s2t1 = MFMA16(k2t1a, q2f0, z);  s2t1 = MFMA16(k2t1b, q2f1, s2t1);

        bf16x8 b1, b2;
#pragma unroll
        for (int r = 0; r < 4; ++r) {
            float e;
            e = __expf(s1t0[r]); l1 += e; b1[r]     = (bf16)e;
            e = __expf(s1t1[r]); l1 += e; b1[4 + r] = (bf16)e;
            e = __expf(s2t0[r]); l2 += e; b2[r]     = (bf16)e;
            e = __expf(s2t1[r]); l2 += e; b2[4 + r] = (bf16)e;
        }

        O1[0] = MFMA16(v0, b1, O1[0]);
        O1[1] = MFMA16(v1, b1, O1[1]);
        O1[2] = MFMA16(v2, b1, O1[2]);
        O1[3] = MFMA16(v3, b1, O1[3]);
        O2[0] = MFMA16(v0, b2, O2[0]);
        O2[1] = MFMA16(v1, b2, O2[1]);
        O2[2] = MFMA16(v2, b2, O2[2]);
        O2[3] = MFMA16(v3, b2, O2[3]);

        __syncthreads();
    }

    l1 += __shfl_xor(l1, 16, 64);  l1 += __shfl_xor(l1, 32, 64);
    l2 += __shfl_xor(l2, 16, 64);  l2 += __shfl_xor(l2, 32, 64);
    if (lane < 16) {
        lbuf[wave][0][lane] = l1;
        lbuf[wave][1][lane] = l2;
    }
    __syncthreads();

    f32x4* rb = (f32x4*)smem;
    if (wave == 4 || wave == 5) {
        f32x4* dst = rb + (wave - 4) * 512;
#pragma unroll
        for (int t = 0; t < 4; ++t) {
            dst[t * 64 + lane]       = O1[t];
            dst[(4 + t) * 64 + lane] = O2[t];
        }
    }
    __syncthreads();
    if (wave == 0 || wave == 1) {
        const f32x4* src = rb + wave * 512;
#pragma unroll
        for (int t = 0; t < 4; ++t) {
            O1[t] += src[t * 64 + lane];
            O2[t] += src[(4 + t) * 64 + lane];
        }
    }
    __syncthreads();
    if (wave == 6 || wave == 7) {
        f32x4* dst = rb + (wave - 6) * 512;
#pragma unroll
        for (int t = 0; t < 4; ++t) {
            dst[t * 64 + lane]       = O1[t];
            dst[(4 + t) * 64 + lane] = O2[t];
        }
    }
    __syncthreads();
    if (wave == 2 || wave == 3) {
        const f32x4* src = rb + (wave - 2) * 512;
#pragma unroll
        for (int t = 0; t < 4; ++t) {
            O1[t] += src[t * 64 + lane];
            O2[t] += src[(4 + t) * 64 + lane];
        }
    }

    float ssum = 0.f, ssq = 0.f;
    if (wave < 4) {
        const float L1 = l1 + lbuf[wave + 4][0][l15];
        const float L2 = l2 + lbuf[wave + 4][1][l15];
        const float lam = __expf(lq1[h] * lk1[h]) - __expf(lq2[h] * lk2[h]) + LAMBDA_INIT;
        const float inv1 = 1.f / L1;
        const float inv2 = lam / L2;
        const size_t row = (size_t)(b * 2048 + qt * 64 + wave * 16 + l15) * 512 + h * 64;
#pragma unroll
        for (int t = 0; t < 4; ++t) {
#pragma unroll
            for (int r = 0; r < 4; ++r) {
                const float val = O1[t][r] * inv1 - O2[t][r] * inv2;
                ssum += val;
                ssq += val * val;
                o[row + t * 16 + quad * 4 + r] = (bf16)val;
            }
        }
    }
#pragma unroll
    for (int off = 1; off < 64; off <<= 1) {
        ssum += __shfl_xor(ssum, off, 64);
        ssq += __shfl_xor(ssq, off, 64);
    }
    if (lane == 0) { sred[wave][0] = ssum; sred[wave][1] = ssq; }
    __syncthreads();
    if (tid == 0) {
        float s0 = 0.f, s1 = 0.f;
        for (int w = 0; w < 8; ++w) { s0 += sred[w][0]; s1 += sred[w][1]; }
        const int bg = b * 4 + (h >> 1);
        atomicAdd(&stats[bg * 2], s0);
        atomicAdd(&stats[bg * 2 + 1], s1);
    }
}

// ---------------------------------------------------------------------------
// Kernel 3: prep for the GN-folded output GEMM (stats-independent):
//   ow_g[n,c] = ow[n,c] * gnw[c]   (bf16)
//   S0[n]     = sum_c gnb[c] * ow[n,c]
// 32 blocks x 256 threads; block owns 16 n-rows; coalesced over c.
// ---------------------------------------------------------------------------
__global__ __launch_bounds__(256) void prep_kernel(
    const float* __restrict__ ow, const float* __restrict__ gnw,
    const float* __restrict__ gnb, bf16* __restrict__ owg,
    float* __restrict__ S0)
{
    __shared__ float red[4];
    const int tid = threadIdx.x;
    const int n0 = blockIdx.x * 16;
    const int c0 = tid, c1 = tid + 256;

    const float gw0 = gnw[c0], gw1 = gnw[c1];
    const float gb0 = gnb[c0], gb1 = gnb[c1];

    for (int n = 0; n < 16; ++n) {
        const size_t rowb = (size_t)(n0 + n) * 512;
        const float w0 = ow[rowb + c0];
        const float w1 = ow[rowb + c1];
        owg[rowb + c0] = (bf16)(w0 * gw0);
        owg[rowb + c1] = (bf16)(w1 * gw1);
        float s = gb0 * w0 + gb1 * w1;
#pragma unroll
        for (int off = 1; off < 64; off <<= 1) s += __shfl_xor(s, off, 64);
        if ((tid & 63) == 0) red[tid >> 6] = s;
        __syncthreads();
        if (tid == 0) S0[n0 + n] = red[0] + red[1] + red[2] + red[3];
        __syncthreads();
    }
}

// ---------------------------------------------------------------------------
// Kernel 4: output GEMM with GN folded algebraically:
// y[m,n] = sum_g rs[g]*(sum_{c in g} o[m,c]*owg[n,c])
//        + S0[n] - sum_g mu[g]*rs[g]*S1[n,g] + ob[n]
// Pure bf16 inner loop (no affine VALU); group fold at kk = 3,7,11,15.
// S1[n,g] computed for free from B-fragment element sums.
// 512 blocks (64 m x 8 n), 64x64 tile, LDS-staged A/B (4 KB each).
// ---------------------------------------------------------------------------
__global__ __launch_bounds__(256) void out_gemm_kernel(
    const bf16* __restrict__ o, const bf16* __restrict__ owg,
    const float* __restrict__ S0, const float* __restrict__ stats,
    const float* __restrict__ ob, float* __restrict__ y)
{
    __shared__ __align__(16) bf16 As[64 * 32];   // 4 KB
    __shared__ __align__(16) bf16 Bs[64 * 32];   // 4 KB

    const int tid = threadIdx.x;
    const int wave = tid >> 6, lane = tid & 63;
    const int l15 = lane & 15, quad = lane >> 4;

    const int mb = blockIdx.x >> 3;          // 64 m-blocks of 64 rows
    const int nb = blockIdx.x & 7;           // 8 n-blocks of 64 cols
    const int b = mb >> 5;                   // batch

    const float N = 128.f * 2048.f;
    float mu[4], rs[4];
#pragma unroll
    for (int g = 0; g < 4; ++g) {
        const float m = stats[(b * 4 + g) * 2] / N;
        const float var = stats[(b * 4 + g) * 2 + 1] / N - m * m;
        mu[g] = m;
        rs[g] = rsqrtf(var + EPS);
    }

    // Staging addresses: wave w stages rows w*16..w*16+15 of the 64x32 tile.
    const int srow = wave * 16 + (lane >> 2);
    const int scol = (lane & 3) * 8;
    const bf16* ag = o + (size_t)(mb * 64 + srow) * 512 + scol;
    const bf16* bg = owg + (size_t)(nb * 64 + srow) * 512 + scol;
    bf16* adst = As + wave * 512;
    bf16* bdst = Bs + wave * 512;

    f32x4 acc[4], tot[4];
#pragma unroll
    for (int i = 0; i < 4; ++i) {
        acc[i] = (f32x4){0.f, 0.f, 0.f, 0.f};
        tot[i] = (f32x4){0.f, 0.f, 0.f, 0.f};
    }
    float s1g[4];
    float s1p = 0.f;
#pragma unroll
    for (int g = 0; g < 4; ++g) s1g[g] = 0.f;

    for (int kk = 0; kk < 16; ++kk) {
        gload_lds16(ag + kk * 32, adst);
        gload_lds16(bg + kk * 32, bdst);
        __syncthreads();

        bf16x8 af[4];
#pragma unroll
        for (int i = 0; i < 4; ++i)
            af[i] = *(const bf16x8*)(As + (i * 16 + l15) * 32 + quad * 8);
        const bf16x8 bf = *(const bf16x8*)(Bs + (wave * 16 + l15) * 32 + quad * 8);

#pragma unroll
        for (int i = 0; i < 4; ++i)
            acc[i] = MFMA16(af[i], bf, acc[i]);

        // S1 partial: this lane's 8 owg values for col n = l15.
#pragma unroll
        for (int j = 0; j < 8; ++j) s1p += (float)bf[j];

        __syncthreads();

        if ((kk & 3) == 3) {
            const int g = kk >> 2;
#pragma unroll
            for (int i = 0; i < 4; ++i) {
#pragma unroll
                for (int r = 0; r < 4; ++r) tot[i][r] += rs[g] * acc[i][r];
                acc[i] = (f32x4){0.f, 0.f, 0.f, 0.f};
            }
            float sg = s1p + __shfl_xor(s1p, 16, 64);
            sg += __shfl_xor(sg, 32, 64);
            s1g[g] = sg;
            s1p = 0.f;
        }
    }

    const int ncol = nb * 64 + wave * 16 + l15;
    float bias = S0[ncol] + ob[ncol];
#pragma unroll
    for (int g = 0; g < 4; ++g) bias -= mu[g] * rs[g] * s1g[g];

#pragma unroll
    for (int i = 0; i < 4; ++i) {
#pragma unroll
        for (int r = 0; r < 4; ++r) {
            const int m = mb * 64 + i * 16 + quad * 4 + r;
            y[(size_t)m * 512 + ncol] = tot[i][r] + bias;
        }
    }
}

// ---------------------------------------------------------------------------
extern "C" void kernel_launch(void* const* d_in, const int* in_sizes, int n_in,
                              void* d_out, int out_size, void* d_ws, size_t ws_size,
                              hipStream_t stream)
{
    const float* x   = (const float*)d_in[0];
    const float* K1w = (const float*)d_in[1];
    const float* K1b = (const float*)d_in[2];
    const float* Q1w = (const float*)d_in[3];
    const float* K2w = (const float*)d_in[4];
    const float* K2b = (const float*)d_in[5];
    const float* Q2w = (const float*)d_in[6];
    const float* Vw  = (const float*)d_in[7];
    const float* lq1 = (const float*)d_in[8];
    const float* lk1 = (const float*)d_in[9];
    const float* lq2 = (const float*)d_in[10];
    const float* lk2 = (const float*)d_in[11];
    const float* gnw = (const float*)d_in[12];
    const float* gnb = (const float*)d_in[13];
    const float* Ow  = (const float*)d_in[14];
    const float* Ob  = (const float*)d_in[15];

    const size_t SZ = (size_t)2 * 8 * 2048 * 64;   // 2M elements per tensor
    bf16* q1 = (bf16*)d_ws;
    bf16* k1 = q1 + SZ;
    bf16* q2 = k1 + SZ;
    bf16* k2 = q2 + SZ;
    bf16* vt = k2 + SZ;
    bf16* o  = vt + SZ;
    bf16* owg = o + SZ;                       // 512x512 bf16 (0.5 MB)
    float* S0 = (float*)(owg + 512 * 512);    // 512 f32
    float* stats = S0 + 512;                  // 16 f32

    hipMemsetAsync(stats, 0, 16 * sizeof(float), stream);

    proj_kernel<<<640, 256, 0, stream>>>(x, Q1w, K1w, Q2w, K2w, Vw, K1b, K2b,
                                         q1, k1, q2, k2, vt);
    prep_kernel<<<32, 256, 0, stream>>>(Ow, gnw, gnb, owg, S0);
    attn_kernel<<<512, 512, 0, stream>>>(q1, k1, q2, k2, vt,
                                         lq1, lk1, lq2, lk2, o, stats);
    out_gemm_kernel<<<512, 256, 0, stream>>>(o, owg, S0, stats, Ob,
                                             (float*)d_out);
}